// Round 4
// baseline (886.869 us; speedup 1.0000x reference)
//
#include <hip/hip_runtime.h>
#include <hip/hip_bf16.h>
#include <math.h>

typedef __hip_bfloat16 bf16;
typedef unsigned short u16t;
typedef __bf16 bfx8 __attribute__((ext_vector_type(8)));
typedef float fx4 __attribute__((ext_vector_type(4)));
typedef unsigned short usx8 __attribute__((ext_vector_type(8)));

constexpr int Bq = 8, Hh = 64, Ww = 64, Nn = 4096, Cc = 384, NH = 8, CH = 1536;
constexpr int Mrows = Bq * Nn;  // 32768
constexpr int NS = 4;           // gram split-K factor
constexpr int NSP = 6;          // attn S split-c factor
constexpr float EPSC = 1e-5f;
constexpr float SCALE = 0.14433756729740643f;  // 48^-0.5

__device__ __forceinline__ float toF(bf16 v) { return __bfloat162float(v); }

__device__ __forceinline__ float ldFlag(const void* p, size_t i, int f) {
    if (f) return __bfloat162float(((const bf16*)p)[i]);
    return ((const float*)p)[i];
}

__device__ __forceinline__ float u2f(u16t u) {
    unsigned int x = ((unsigned int)u) << 16;
    float fv;
    __builtin_memcpy(&fv, &x, 4);
    return fv;
}
__device__ __forceinline__ u16t f2u(float v) {
    bf16 h = __float2bfloat16(v);
    u16t u;
    __builtin_memcpy(&u, &h, 2);
    return u;
}
__device__ __forceinline__ fx4 mfma16(usx8 a, usx8 b, fx4 c) {
    return __builtin_amdgcn_mfma_f32_16x16x32_bf16(
        __builtin_bit_cast(bfx8, a), __builtin_bit_cast(bfx8, b), c, 0, 0, 0);
}

// ---- probe: bf16 N(0,1) data never has exponent>=134 (|v|>=128); fp32 halves do. ----
__global__ __launch_bounds__(256) void probe_k(const void* __restrict__ p, int* __restrict__ flag) {
    int t = threadIdx.x;
    int bad = 0;
    for (int i = t; i < 4096; i += 256) {
        unsigned short u = ((const unsigned short*)p)[i];
        unsigned e = (u >> 7) & 0xFF;
        if (e >= 134) bad++;
    }
    __shared__ int sh[256];
    sh[t] = bad;
    __syncthreads();
    for (int s = 128; s > 0; s >>= 1) {
        if (t < s) sh[t] += sh[t + s];
        __syncthreads();
    }
    if (t == 0) flag[0] = (sh[0] < 64) ? 1 : 0;  // 1 = bf16, 0 = fp32
}

// ---- bf16 copies of LN2 gamma/beta for vectorized LN-on-load in fc1 ----
__global__ __launch_bounds__(384) void prep_k(const void* __restrict__ g,
                                              const void* __restrict__ b,
                                              u16t* __restrict__ gB, u16t* __restrict__ bB,
                                              const int* __restrict__ flagp) {
    int f = *flagp;
    int t = threadIdx.x;
    gB[t] = f2u(ldFlag(g, t, f));
    bB[t] = f2u(ldFlag(b, t, f));
}

// ---- fused depthwise 3x3 conv + bias + residual (+LN normalize OR +stats) ----
template <int INM, int MODE>
__global__ __launch_bounds__(384) void dwconv_ln(const void* __restrict__ xin,
                                                 const void* __restrict__ w,
                                                 const void* __restrict__ bias,
                                                 bf16* __restrict__ out,
                                                 const void* __restrict__ g,
                                                 const void* __restrict__ bb,
                                                 float* __restrict__ mu,
                                                 float* __restrict__ rs,
                                                 const int* __restrict__ flagp) {
    int f = *flagp;
    int c = threadIdx.x;      // channel 0..383
    int w0 = blockIdx.x * 8;  // 0..56
    int hh = blockIdx.y;
    int b = blockIdx.z;
    size_t base = (size_t)b * Nn * Cc;
    float wreg[9];
#pragma unroll
    for (int j = 0; j < 9; j++) wreg[j] = ldFlag(w, c * 9 + j, f);
    float bc = ldFlag(bias, c, f);
    float v[3][10];
#pragma unroll
    for (int ky = 0; ky < 3; ky++) {
        int yy = hh + ky - 1;
        bool rv = (yy >= 0 && yy < Hh);
#pragma unroll
        for (int j = 0; j < 10; j++) {
            int xx = w0 - 1 + j;
            bool cv = (xx >= 0 && xx < Ww);
            float val = 0.f;
            if (rv && cv) {
                size_t idx = base + (size_t)(yy * Ww + xx) * Cc + c;
                val = (INM == 1) ? toF(((const bf16*)xin)[idx]) : ldFlag(xin, idx, f);
            }
            v[ky][j] = val;
        }
    }
    float r[8], s[8], s2[8];
#pragma unroll
    for (int p = 0; p < 8; p++) {
        float a = bc;
#pragma unroll
        for (int ky = 0; ky < 3; ky++)
#pragma unroll
            for (int kx = 0; kx < 3; kx++) a += v[ky][p + kx] * wreg[ky * 3 + kx];
        r[p] = v[1][p + 1] + a;
        s[p] = r[p];
        s2[p] = r[p] * r[p];
    }
#pragma unroll
    for (int off = 32; off > 0; off >>= 1) {
#pragma unroll
        for (int p = 0; p < 8; p++) {
            s[p] += __shfl_down(s[p], off, 64);
            s2[p] += __shfl_down(s2[p], off, 64);
        }
    }
    __shared__ float shS[6][8], shS2[6][8];
    __shared__ float shMu[8], shRs[8];
    int wv = c >> 6, ln = c & 63;
    if (ln == 0) {
#pragma unroll
        for (int p = 0; p < 8; p++) {
            shS[wv][p] = s[p];
            shS2[wv][p] = s2[p];
        }
    }
    __syncthreads();
    if (c < 8) {
        float S = 0, S2 = 0;
#pragma unroll
        for (int q = 0; q < 6; q++) {
            S += shS[q][c];
            S2 += shS2[q][c];
        }
        float m = S * (1.0f / Cc);
        float var = S2 * (1.0f / Cc) - m * m;
        float rr = rsqrtf(var + EPSC);
        if (MODE == 0) {
            shMu[c] = m;
            shRs[c] = rr;
        } else {
            int row = b * Nn + hh * Ww + w0 + c;
            mu[row] = m;
            rs[row] = rr;
        }
    }
    if (MODE == 0) {
        __syncthreads();
        float gc = ldFlag(g, c, f), bbc = ldFlag(bb, c, f);
#pragma unroll
        for (int p = 0; p < 8; p++) {
            size_t oi = base + (size_t)(hh * Ww + w0 + p) * Cc + c;
            out[oi] = __float2bfloat16((r[p] - shMu[p]) * shRs[p] * gc + bbc);
        }
    } else {
#pragma unroll
        for (int p = 0; p < 8; p++) {
            size_t oi = base + (size_t)(hh * Ww + w0 + p) * Cc + c;
            out[oi] = __float2bfloat16(r[p]);
        }
    }
}

// ------- in-place split-K reduce: Gp[b][0] = sum_s Gp[b][s] (float4) -------
__global__ __launch_bounds__(256) void reduceG_k(float* __restrict__ Gp) {
    const size_t Q = (size_t)Cc * Cc / 4;  // 36864 float4 per matrix
    size_t j = (size_t)blockIdx.x * 256 + threadIdx.x;
    int b = (int)(j / Q);
    size_t i4 = j % Q;
    fx4* G4 = (fx4*)Gp;
    size_t base = (size_t)b * NS * Q;
    fx4 a = G4[base + i4];
#pragma unroll
    for (int s = 1; s < NS; s++) a += G4[base + (size_t)s * Q + i4];
    G4[base + i4] = a;
}

// ------- scalar tiled GEMM (kept for the small fp32 P = Gsum @ Wv step) -------
template <int AM, int OM, int WM, bool GELU, bool LNA, int RES, int AR>
__global__ __launch_bounds__(256) void gemm_k(const void* __restrict__ A, size_t aBatch,
                                              const void* __restrict__ W, size_t wBatch,
                                              int ldw, int colOff,
                                              const void* __restrict__ bias,
                                              const bf16* __restrict__ resid, size_t rBatch,
                                              const float* __restrict__ mu,
                                              const float* __restrict__ rs, size_t sBatch,
                                              const void* __restrict__ cg,
                                              const void* __restrict__ cb,
                                              void* __restrict__ out, size_t oBatch,
                                              size_t outRow0,
                                              int M, int K, int Nc,
                                              const int* __restrict__ flagp) {
    int f = *flagp;
    int z = blockIdx.z;
    const size_t MK = (size_t)M * K;
    __shared__ float As[16][68];
    __shared__ float Bs[16][68];
    int t = threadIdx.x;
    int tx = t & 15, ty = t >> 4;
    int row0 = blockIdx.x * 64, n0 = blockIdx.y * 64;
    float acc[4][4] = {};
    for (int k0 = 0; k0 < K; k0 += 16) {
#pragma unroll
        for (int i = 0; i < 4; i++) {
            int lin = i * 256 + t;
            int kk = lin & 15, m = lin >> 4;
            size_t ai = (size_t)z * aBatch + (size_t)(row0 + m) * K + k0 + kk;
            float v;
            if (AR > 1) {
                v = 0;
#pragma unroll
                for (int s = 0; s < AR; s++) v += ((const float*)A)[ai + (size_t)s * MK];
            } else {
                v = (AM == 0) ? ((const float*)A)[ai] : toF(((const bf16*)A)[ai]);
            }
            if (LNA) {
                float muv = mu[z * sBatch + row0 + m], rsv = rs[z * sBatch + row0 + m];
                v = (v - muv) * rsv * ldFlag(cg, k0 + kk, f) + ldFlag(cb, k0 + kk, f);
            }
            As[kk][m] = v;
        }
#pragma unroll
        for (int i = 0; i < 4; i++) {
            int lin = i * 256 + t;
            int nn2 = lin & 63, kk = lin >> 6;
            size_t wi = (size_t)z * wBatch + (size_t)(k0 + kk) * ldw + colOff + n0 + nn2;
            Bs[kk][nn2] = (WM == 1) ? toF(((const bf16*)W)[wi]) : ldFlag(W, wi, f);
        }
        __syncthreads();
#pragma unroll
        for (int kk = 0; kk < 16; kk++) {
            float a[4], bv[4];
#pragma unroll
            for (int i = 0; i < 4; i++) a[i] = As[kk][ty * 4 + i];
#pragma unroll
            for (int j = 0; j < 4; j++) bv[j] = Bs[kk][tx * 4 + j];
#pragma unroll
            for (int i = 0; i < 4; i++)
#pragma unroll
                for (int j = 0; j < 4; j++) acc[i][j] += a[i] * bv[j];
        }
        __syncthreads();
    }
#pragma unroll
    for (int i = 0; i < 4; i++) {
        int m = row0 + ty * 4 + i;
#pragma unroll
        for (int j = 0; j < 4; j++) {
            int nn2 = n0 + tx * 4 + j;
            float v = acc[i][j];
            if (bias) v += ldFlag(bias, nn2, f);
            if (GELU) v = 0.5f * v * (1.0f + erff(v * 0.70710678118654752f));
            if (RES == 1) v += toF(resid[(size_t)z * rBatch + (size_t)m * Nc + nn2]);
            size_t oi = (size_t)z * oBatch + (outRow0 + m) * (size_t)Nc + nn2;
            if (OM == 2) ((float*)out)[oi] = v;
            else if (OM == 1) ((bf16*)out)[oi] = __float2bfloat16(v);
            else {
                if (f) ((bf16*)out)[oi] = __float2bfloat16(v);
                else ((float*)out)[oi] = v;
            }
        }
    }
}

// ------- weight transpose + bf16 convert: WT[n][k] = W[k][n] -------
__global__ __launch_bounds__(256) void transpose_k(const void* __restrict__ W,
                                                   u16t* __restrict__ WT,
                                                   int K, int N,
                                                   const int* __restrict__ flagp) {
    int f = *flagp;
    __shared__ u16t T[64][72];
    int n0 = blockIdx.x * 64, k0 = blockIdx.y * 64;
    int t = threadIdx.x;
#pragma unroll
    for (int i = 0; i < 16; i++) {
        int lin = i * 256 + t;
        int kk = lin >> 6, nn = lin & 63;
        T[nn][kk] = f2u(ldFlag(W, (size_t)(k0 + kk) * N + n0 + nn, f));
    }
    __syncthreads();
#pragma unroll
    for (int i = 0; i < 16; i++) {
        int lin = i * 256 + t;
        int nn = lin >> 6, kk = lin & 63;
        WT[(size_t)(n0 + nn) * K + k0 + kk] = T[nn][kk];
    }
}

// ------- MFMA GEMM: C[m][n] = A[m][:] . BT[n][:]  (BT pre-transposed, bf16) -------
// 128x128 tile, 4 waves (2x2), 16B-chunk XOR-swizzled [128][64] LDS (32 KB total).
template <int AMODE, int OM, bool GELU, int RES>
__global__ __launch_bounds__(256) void gemm_mfma(
    const u16t* __restrict__ A, size_t aBatch,
    const u16t* __restrict__ BT, size_t btBatch,
    const void* __restrict__ bias,
    const u16t* __restrict__ resid, size_t rBatch,
    const float* __restrict__ mu, const float* __restrict__ rs, size_t sBatch,
    const u16t* __restrict__ gbf, const u16t* __restrict__ bbf,
    void* __restrict__ out, size_t oBatch, size_t outRow0,
    int K, int N, const int* __restrict__ flagp) {
    int f = *flagp;
    int z = blockIdx.z;
    int t = threadIdx.x;
    int row0 = blockIdx.x * 128, n0 = blockIdx.y * 128;
    __shared__ u16t As[128][64];
    __shared__ u16t Bs[128][64];
    const u16t* Ab = A + (size_t)z * aBatch;
    const u16t* Bb = BT + (size_t)z * btBatch;
    const int sm = t >> 3;    // staging row 0..31 (per i-block of 32)
    const int sk8 = t & 7;    // 16B chunk 0..7
    float muv[4], rsv[4];
    if (AMODE == 1) {
#pragma unroll
        for (int i = 0; i < 4; i++) {
            int m = row0 + i * 32 + sm;
            muv[i] = mu[(size_t)z * sBatch + m];
            rsv[i] = rs[(size_t)z * sBatch + m];
        }
    }
    usx8 ra[4], rb[4];
    auto ldstep = [&](int k0) {
#pragma unroll
        for (int i = 0; i < 4; i++) {
            ra[i] = *(const usx8*)&Ab[(size_t)(row0 + i * 32 + sm) * K + k0 + sk8 * 8];
            rb[i] = *(const usx8*)&Bb[(size_t)(n0 + i * 32 + sm) * K + k0 + sk8 * 8];
        }
    };
    auto wrstep = [&](int k0) {
        usx8 ga, ba;
        if (AMODE == 1) {
            ga = *(const usx8*)&gbf[k0 + sk8 * 8];
            ba = *(const usx8*)&bbf[k0 + sk8 * 8];
        }
#pragma unroll
        for (int i = 0; i < 4; i++) {
            int row = i * 32 + sm;
            int dst = (sk8 ^ (row & 7)) << 3;
            if (AMODE == 1) {
                usx8 v;
#pragma unroll
                for (int j = 0; j < 8; j++)
                    v[j] = f2u((u2f(ra[i][j]) - muv[i]) * rsv[i] * u2f(ga[j]) + u2f(ba[j]));
                *(usx8*)&As[row][dst] = v;
            } else {
                *(usx8*)&As[row][dst] = ra[i];
            }
            *(usx8*)&Bs[row][dst] = rb[i];
        }
    };
    fx4 acc[4][4];
    fx4 zz = {0.f, 0.f, 0.f, 0.f};
#pragma unroll
    for (int i = 0; i < 4; i++)
#pragma unroll
        for (int j = 0; j < 4; j++) acc[i][j] = zz;
    int lane = t & 63, w = t >> 6;
    int wr = (w >> 1) * 64, wc = (w & 1) * 64;
    int lr = lane & 15, lg = lane >> 4;
    ldstep(0);
    wrstep(0);
    __syncthreads();
    int KT = K / 64;
    for (int kt = 0; kt < KT; kt++) {
        if (kt + 1 < KT) ldstep((kt + 1) * 64);
#pragma unroll
        for (int ks = 0; ks < 2; ks++) {
            usx8 af[4], bfv[4];
#pragma unroll
            for (int r = 0; r < 4; r++) {
                int row = wr + r * 16 + lr;
                af[r] = *(const usx8*)&As[row][((4 * ks + lg) ^ (row & 7)) << 3];
            }
#pragma unroll
            for (int c = 0; c < 4; c++) {
                int row = wc + c * 16 + lr;
                bfv[c] = *(const usx8*)&Bs[row][((4 * ks + lg) ^ (row & 7)) << 3];
            }
#pragma unroll
            for (int r = 0; r < 4; r++)
#pragma unroll
                for (int c = 0; c < 4; c++)
                    acc[r][c] = mfma16(af[r], bfv[c], acc[r][c]);
        }
        __syncthreads();
        if (kt + 1 < KT) {
            wrstep((kt + 1) * 64);
            __syncthreads();
        }
    }
#pragma unroll
    for (int r = 0; r < 4; r++) {
#pragma unroll
        for (int c = 0; c < 4; c++) {
            int gc = n0 + wc + c * 16 + lr;
            float bv = bias ? ldFlag(bias, gc, f) : 0.0f;
#pragma unroll
            for (int q = 0; q < 4; q++) {
                int m = row0 + wr + r * 16 + lg * 4 + q;
                float v = acc[r][c][q] + bv;
                if (GELU) v = 0.5f * v * (1.0f + erff(v * 0.70710678118654752f));
                if (RES == 1) v += u2f(resid[(size_t)z * rBatch + (size_t)m * N + gc]);
                if (RES == 2) v += u2f(Ab[(size_t)m * K + gc]);
                size_t oi = (size_t)z * oBatch + (outRow0 + m) * (size_t)N + gc;
                if (OM == 1) ((u16t*)out)[oi] = f2u(v);
                else {
                    if (f) ((u16t*)out)[oi] = f2u(v);
                    else ((float*)out)[oi] = v;
                }
            }
        }
    }
}

// ------- MFMA gram split-K: Gp[b][sp] = lnS^T lnS over 1024 rows (lnS pre-normalized) -------
__global__ __launch_bounds__(256) void gram_mfma(const u16t* __restrict__ sc,
                                                 float* __restrict__ Gp) {
    int bx = blockIdx.x, sp = blockIdx.y, b = blockIdx.z;
    int ci0 = (bx / 3) * 128, cj0 = (bx % 3) * 128;
    __shared__ u16t As[128][72];
    __shared__ u16t Bs[128][72];
    int t = threadIdx.x;
    const int scc = (t * 8) & 127;  // fixed channel offset per thread
    const int snn = t >> 4;         // 0..15
    const int RPS = Nn / NS;        // 1024
    int rowbase = b * Nn + sp * RPS;
    usx8 ra[4], rb[4];
    auto ldstep = [&](int nn0) {
#pragma unroll
        for (int i = 0; i < 4; i++) {
            int r = rowbase + nn0 + i * 16 + snn;
            ra[i] = *(const usx8*)&sc[(size_t)r * Cc + ci0 + scc];
            rb[i] = *(const usx8*)&sc[(size_t)r * Cc + cj0 + scc];
        }
    };
    auto wrstep = [&]() {
#pragma unroll
        for (int i = 0; i < 4; i++) {
            int n = i * 16 + snn;
            int q = n >> 3, nl = n & 7;
#pragma unroll
            for (int j = 0; j < 8; j++) {
                int c = scc + j;
                int swz = ((c >> 3) ^ (c >> 6)) & 7;
                int po = ((q ^ swz) << 3) + nl;
                As[c][po] = ra[i][j];
                Bs[c][po] = rb[i][j];
            }
        }
    };
    fx4 acc[4][4];
    fx4 zz = {0.f, 0.f, 0.f, 0.f};
#pragma unroll
    for (int i = 0; i < 4; i++)
#pragma unroll
        for (int j = 0; j < 4; j++) acc[i][j] = zz;
    int lane = t & 63, w = t >> 6;
    int wr = (w >> 1) * 64, wc = (w & 1) * 64;
    int lr = lane & 15, lg = lane >> 4;
    ldstep(0);
    wrstep();
    __syncthreads();
    const int KT = RPS / 64;  // 16
    for (int kt = 0; kt < KT; kt++) {
        if (kt + 1 < KT) ldstep((kt + 1) * 64);
#pragma unroll
        for (int ks = 0; ks < 2; ks++) {
            usx8 af[4], bfv[4];
#pragma unroll
            for (int r = 0; r < 4; r++) {
                int ch = wr + r * 16 + lr;
                int swz = ((ch >> 3) ^ (ch >> 6)) & 7;
                af[r] = *(const usx8*)&As[ch][((ks * 4 + lg) ^ swz) << 3];
            }
#pragma unroll
            for (int c = 0; c < 4; c++) {
                int ch = wc + c * 16 + lr;
                int swz = ((ch >> 3) ^ (ch >> 6)) & 7;
                bfv[c] = *(const usx8*)&Bs[ch][((ks * 4 + lg) ^ swz) << 3];
            }
#pragma unroll
            for (int r = 0; r < 4; r++)
#pragma unroll
                for (int c = 0; c < 4; c++)
                    acc[r][c] = mfma16(af[r], bfv[c], acc[r][c]);
        }
        __syncthreads();
        if (kt + 1 < KT) {
            wrstep();
            __syncthreads();
        }
    }
    float* dst = Gp + ((size_t)b * NS + sp) * (size_t)Cc * Cc;
#pragma unroll
    for (int r = 0; r < 4; r++)
#pragma unroll
        for (int c = 0; c < 4; c++)
#pragma unroll
            for (int q = 0; q < 4; q++)
                dst[(size_t)(ci0 + wr + r * 16 + lg * 4 + q) * Cc + cj0 + wc + c * 16 + lr] =
                    acc[r][c][q];
}

// ------- S partials: Sp[b,h,sp] = Wk_h[c-range]^T @ P_b[c-range, h]. grid (NH, Bq, NSP). -------
__global__ __launch_bounds__(256) void attn_part_k(const float* __restrict__ P,
                                                   const void* __restrict__ kv_w,
                                                   float* __restrict__ Sp,
                                                   const int* __restrict__ flagp) {
    int f = *flagp;
    int hd = blockIdx.x;
    int b = blockIdx.y;
    int sp = blockIdx.z;
    int c0 = sp * 64;
    int t = threadIdx.x;
    const float* Pb = P + (size_t)b * Cc * Cc;
    __shared__ float Pc[64][49];
    __shared__ float Wkc[64][49];
    for (int idx = t; idx < 3072; idx += 256) {
        int r = idx / 48, e = idx % 48;
        int c = c0 + r;
        Pc[r][e] = Pb[(size_t)c * Cc + hd * 48 + e];
        Wkc[r][e] = ldFlag(kv_w, (size_t)c * 768 + hd * 48 + e, f);
    }
    __syncthreads();
    int obase = t * 9;
    float acc[9] = {};
#pragma unroll
    for (int r = 0; r < 64; r++) {
#pragma unroll
        for (int j = 0; j < 9; j++) {
            int d = (obase + j) / 48, e = (obase + j) % 48;
            acc[j] += Wkc[r][d] * Pc[r][e];
        }
    }
    float* dst = Sp + (((size_t)b * NH + hd) * NSP + sp) * 2304;
#pragma unroll
    for (int j = 0; j < 9; j++) dst[obase + j] = acc[j];
}

// ------- sum partials + softmax rows. grid (NH, Bq). -------
__global__ __launch_bounds__(256) void attn_soft_k(const float* __restrict__ Sp,
                                                   float* __restrict__ attn) {
    int hd = blockIdx.x;
    int b = blockIdx.y;
    int t = threadIdx.x;
    __shared__ float Ss[48][49];
    const float* src = Sp + (((size_t)b * NH + hd) * NSP) * 2304;
    for (int idx = t; idx < 2304; idx += 256) {
        float s = 0;
#pragma unroll
        for (int sp = 0; sp < NSP; sp++) s += src[sp * 2304 + idx];
        Ss[idx / 48][idx % 48] = s * SCALE;
    }
    __syncthreads();
    if (t < 48) {
        float m = -1e30f;
#pragma unroll
        for (int e = 0; e < 48; e++) m = fmaxf(m, Ss[t][e]);
        float ex[48];
        float sum = 0;
#pragma unroll
        for (int e = 0; e < 48; e++) {
            ex[e] = expf(Ss[t][e] - m);
            sum += ex[e];
        }
        float inv = 1.0f / sum;
#pragma unroll
        for (int e = 0; e < 48; e++)
            attn[((size_t)b * NH + hd) * 2304 + t * 48 + e] = ex[e] * inv;
    }
}

// ------- Wtilde[b][c][h*48+d] = sum_e Wq[c, h*48+e] * attn[b,h,d,e]. grid (6, NH, Bq). -------
__global__ __launch_bounds__(256) void wtilde_k(const void* __restrict__ q_w,
                                                const float* __restrict__ attn,
                                                bf16* __restrict__ Wt_,
                                                const int* __restrict__ flagp) {
    int f = *flagp;
    int c0 = blockIdx.x * 64;
    int hd = blockIdx.y;
    int b = blockIdx.z;
    int t = threadIdx.x;
    __shared__ float at[48][48];
    __shared__ float wq[64][48];
    const float* ab = attn + ((size_t)b * NH + hd) * 2304;
    for (int o = t; o < 2304; o += 256) at[o / 48][o % 48] = ab[o];
    for (int o = t; o < 3072; o += 256) {
        int cc = o / 48, e = o % 48;
        wq[cc][e] = ldFlag(q_w, (size_t)(c0 + cc) * Cc + hd * 48 + e, f);
    }
    __syncthreads();
    bf16* outb = Wt_ + (size_t)b * Cc * Cc;
    for (int o = t; o < 3072; o += 256) {
        int cc = o / 48, d = o % 48;
        float s = 0;
#pragma unroll
        for (int e = 0; e < 48; e++) s += wq[cc][e] * at[d][e];
        outb[(size_t)(c0 + cc) * Cc + hd * 48 + d] = __float2bfloat16(s);
    }
}

extern "C" void kernel_launch(void* const* d_in, const int* in_sizes, int n_in,
                              void* d_out, int out_size, void* d_ws, size_t ws_size,
                              hipStream_t stream) {
    (void)in_sizes; (void)n_in; (void)out_size;
    const void* x = d_in[0];
    const void* srcp = d_in[1];
    const void* cpe0_w = d_in[4];
    const void* cpe0_b = d_in[5];
    const void* cpe1_w = d_in[6];
    const void* cpe1_b = d_in[7];
    const void* n1g = d_in[8];
    const void* n1b = d_in[9];
    const void* q_w = d_in[10];
    const void* kv_w = d_in[11];
    const void* proj_w = d_in[12];
    const void* proj_b = d_in[13];
    const void* n2g = d_in[14];
    const void* n2b = d_in[15];
    const void* fc1_w = d_in[16];
    const void* fc1_b = d_in[17];
    const void* fc2_w = d_in[18];
    const void* fc2_b = d_in[19];
    char* ws = (char*)d_ws;

    // ---- workspace layout ----
    const size_t CcCc = (size_t)Cc * Cc;
    const size_t NnCc = (size_t)Nn * Cc;
    const size_t SLOT = (size_t)Mrows * Cc * sizeof(bf16);  // 25,165,824
    int* flag = (int*)ws;
    bf16* s0 = (bf16*)(ws + 64);            // lnS -> Sp (attn partials) -> x2 -> h1c
    bf16* s1 = (bf16*)(ws + 64 + SLOT);     // Gp (18.9MB fp32) -> WeffT (bf16) -> x3
    float* Gp = (float*)s1;
    u16t* WeffT = (u16t*)s1;                // [Bq][384(c_out)][384(c_in)] bf16
    bf16* x3 = s1;
    float* P = (float*)(ws + 64 + 2 * SLOT);        // 4,718,592 [Bq][384x384] fp32
    bf16* Wt_ = (bf16*)P;                           // alias (P dead after attn_part)
    u16t* projT = (u16t*)((char*)P + 2359296);      // [c_out][e] bf16
    u16t* fc1T = (u16t*)P;                          // [1536][384] bf16, after Weff gemm
    u16t* fc2T = (u16t*)((char*)P + 1179648);       // [384][1536] bf16
    float* attnB = (float*)(ws + 64 + 2 * SLOT + 4718592);  // 589,824
    float* mu2 = (float*)(ws + 64 + 2 * SLOT + 4718592 + 589824);
    float* rs2 = mu2 + Mrows;
    u16t* gB = (u16t*)(rs2 + Mrows);  // 384 bf16 LN2 gamma
    u16t* bB = gB + 384;              // 384 bf16 LN2 beta
    bf16* lnS = s0;
    float* Sp = (float*)s0;  // attn partials [Bq][NH][NSP][2304] fp32 = 3.5 MB (lnS dead)
    bf16* x2 = s0;
    u16t* h1c = (u16t*)s0;  // CR=8192 -> 25.17 MB, exact fit
    const size_t NEED = (size_t)((char*)(bB + 384) - ws);
    if (ws_size < NEED) return;

    bf16* lnX = (bf16*)d_out;  // d_out as bf16 scratch (dead before final writes)

    probe_k<<<1, 256, 0, stream>>>(x, flag);
    prep_k<<<1, 384, 0, stream>>>(n2g, n2b, gB, bB, flag);

    // 1. lnX = LN1(cpe0(x)) fused
    dwconv_ln<2, 0><<<dim3(Ww / 8, Hh, Bq), 384, 0, stream>>>(
        x, cpe0_w, cpe0_b, lnX, n1g, n1b, nullptr, nullptr, flag);

    // 2. lnS = LN1(cpe0(source)) fused -> MFMA gram partials -> in-place reduce
    dwconv_ln<2, 0><<<dim3(Ww / 8, Hh, Bq), 384, 0, stream>>>(
        srcp, cpe0_w, cpe0_b, lnS, n1g, n1b, nullptr, nullptr, flag);
    gram_mfma<<<dim3(9, NS, Bq), 256, 0, stream>>>((const u16t*)lnS, Gp);
    reduceG_k<<<(Bq * CcCc / 4) / 256, 256, 0, stream>>>(Gp);

    // 3. P_b = Gsum_b @ Wv   (fp32 scalar; Wv = kv_w cols 384..767)
    gemm_k<0, 2, 2, false, false, 0, 1><<<dim3(6, 6, Bq), 256, 0, stream>>>(
        Gp, (size_t)NS * CcCc, kv_w, 0, 768, 384, nullptr, nullptr, 0,
        nullptr, nullptr, 0, nullptr, nullptr, P, CcCc, 0, Cc, Cc, Cc, flag);

    // 4. attn: split-c partials (into dead s0) -> softmax -> fold into WeffT
    attn_part_k<<<dim3(NH, Bq, NSP), 256, 0, stream>>>(P, kv_w, Sp, flag);
    attn_soft_k<<<dim3(NH, Bq), 256, 0, stream>>>(Sp, attnB);
    wtilde_k<<<dim3(6, NH, Bq), 256, 0, stream>>>(q_w, attnB, Wt_, flag);
    transpose_k<<<dim3(6, 6), 256, 0, stream>>>(proj_w, projT, Cc, Cc, flag);
    gemm_mfma<0, 1, false, 0><<<dim3(3, 3, Bq), 256, 0, stream>>>(
        projT, 0, (const u16t*)Wt_, CcCc, nullptr, nullptr, 0,
        nullptr, nullptr, 0, nullptr, nullptr, WeffT, CcCc, 0, Cc, Cc, flag);

    // MLP weight transposes (P region free of Wt_ after Weff gemm; stream-ordered)
    transpose_k<<<dim3(24, 6), 256, 0, stream>>>(fc1_w, fc1T, Cc, CH, flag);
    transpose_k<<<dim3(6, 24), 256, 0, stream>>>(fc2_w, fc2T, CH, Cc, flag);

    // 5. x2 = lnX + lnX @ Weff_b + proj_b   (plain MFMA, RES=2 adds A element)
    gemm_mfma<0, 1, false, 2><<<dim3(32, 3, Bq), 256, 0, stream>>>(
        (const u16t*)lnX, NnCc, WeffT, CcCc, proj_b, nullptr, 0,
        nullptr, nullptr, 0, nullptr, nullptr, x2, NnCc, 0, Cc, Cc, flag);

    // 6. x3 = cpe1(x2) raw + LN2 stats (fused)
    dwconv_ln<1, 1><<<dim3(Ww / 8, Hh, Bq), 384, 0, stream>>>(
        x2, cpe1_w, cpe1_b, x3, nullptr, nullptr, mu2, rs2, flag);

    // 7. MLP in 8192-row chunks: out = x3 + gelu(LN2(x3)@fc1+b1)@fc2+b2
    constexpr int CR = 8192;
    for (int ch = 0; ch < Mrows / CR; ch++) {
        size_t roff = (size_t)ch * CR;
        gemm_mfma<1, 1, true, 0><<<dim3(CR / 128, CH / 128, 1), 256, 0, stream>>>(
            (const u16t*)x3 + roff * Cc, 0, fc1T, 0, fc1_b, nullptr, 0,
            mu2 + roff, rs2 + roff, 0, gB, bB, h1c, 0, 0, Cc, CH, flag);
        gemm_mfma<0, 0, false, 1><<<dim3(CR / 128, Cc / 128, 1), 256, 0, stream>>>(
            h1c, 0, fc2T, 0, fc2_b, (const u16t*)x3 + roff * Cc, 0,
            nullptr, nullptr, 0, nullptr, nullptr, d_out, 0, roff, CH, Cc, flag);
    }
}

// Round 5
// 801.410 us; speedup vs baseline: 1.1066x; 1.1066x over previous
//
#include <hip/hip_runtime.h>
#include <hip/hip_bf16.h>
#include <math.h>

typedef __hip_bfloat16 bf16;
typedef unsigned short u16t;
typedef __bf16 bfx8 __attribute__((ext_vector_type(8)));
typedef float fx4 __attribute__((ext_vector_type(4)));
typedef unsigned short usx8 __attribute__((ext_vector_type(8)));

constexpr int Bq = 8, Hh = 64, Ww = 64, Nn = 4096, Cc = 384, NH = 8, CH = 1536;
constexpr int Mrows = Bq * Nn;  // 32768
constexpr int NS = 4;           // gram split-K factor
constexpr int NSP = 6;          // attn S split-c factor
constexpr float EPSC = 1e-5f;
constexpr float SCALE = 0.14433756729740643f;  // 48^-0.5

__device__ __forceinline__ float toF(bf16 v) { return __bfloat162float(v); }

__device__ __forceinline__ float ldFlag(const void* p, size_t i, int f) {
    if (f) return __bfloat162float(((const bf16*)p)[i]);
    return ((const float*)p)[i];
}

__device__ __forceinline__ float u2f(u16t u) {
    unsigned int x = ((unsigned int)u) << 16;
    float fv;
    __builtin_memcpy(&fv, &x, 4);
    return fv;
}
__device__ __forceinline__ u16t f2u(float v) {
    bf16 h = __float2bfloat16(v);
    u16t u;
    __builtin_memcpy(&u, &h, 2);
    return u;
}
__device__ __forceinline__ fx4 mfma16(usx8 a, usx8 b, fx4 c) {
    return __builtin_amdgcn_mfma_f32_16x16x32_bf16(
        __builtin_bit_cast(bfx8, a), __builtin_bit_cast(bfx8, b), c, 0, 0, 0);
}

// async global->LDS 16B copy; lds dest is wave-uniform base + lane*16
__device__ __forceinline__ void gload16(const void* g, void* l) {
    __builtin_amdgcn_global_load_lds(
        reinterpret_cast<const __attribute__((address_space(1))) unsigned int*>(
            reinterpret_cast<uintptr_t>(g)),
        reinterpret_cast<__attribute__((address_space(3))) unsigned int*>(
            reinterpret_cast<uintptr_t>(l)),
        16, 0, 0);
}

// ---- probe: bf16 N(0,1) data never has exponent>=134 (|v|>=128); fp32 halves do. ----
__global__ __launch_bounds__(256) void probe_k(const void* __restrict__ p, int* __restrict__ flag) {
    int t = threadIdx.x;
    int bad = 0;
    for (int i = t; i < 4096; i += 256) {
        unsigned short u = ((const unsigned short*)p)[i];
        unsigned e = (u >> 7) & 0xFF;
        if (e >= 134) bad++;
    }
    __shared__ int sh[256];
    sh[t] = bad;
    __syncthreads();
    for (int s = 128; s > 0; s >>= 1) {
        if (t < s) sh[t] += sh[t + s];
        __syncthreads();
    }
    if (t == 0) flag[0] = (sh[0] < 64) ? 1 : 0;  // 1 = bf16, 0 = fp32
}

// ---- fused depthwise 3x3 conv + bias + residual (+LN normalize OR +stats) ----
template <int INM, int MODE>
__global__ __launch_bounds__(384) void dwconv_ln(const void* __restrict__ xin,
                                                 const void* __restrict__ w,
                                                 const void* __restrict__ bias,
                                                 bf16* __restrict__ out,
                                                 const void* __restrict__ g,
                                                 const void* __restrict__ bb,
                                                 float* __restrict__ mu,
                                                 float* __restrict__ rs,
                                                 const int* __restrict__ flagp) {
    int f = *flagp;
    int c = threadIdx.x;      // channel 0..383
    int w0 = blockIdx.x * 8;  // 0..56
    int hh = blockIdx.y;
    int b = blockIdx.z;
    size_t base = (size_t)b * Nn * Cc;
    float wreg[9];
#pragma unroll
    for (int j = 0; j < 9; j++) wreg[j] = ldFlag(w, c * 9 + j, f);
    float bc = ldFlag(bias, c, f);
    float v[3][10];
#pragma unroll
    for (int ky = 0; ky < 3; ky++) {
        int yy = hh + ky - 1;
        bool rv = (yy >= 0 && yy < Hh);
#pragma unroll
        for (int j = 0; j < 10; j++) {
            int xx = w0 - 1 + j;
            bool cv = (xx >= 0 && xx < Ww);
            float val = 0.f;
            if (rv && cv) {
                size_t idx = base + (size_t)(yy * Ww + xx) * Cc + c;
                val = (INM == 1) ? toF(((const bf16*)xin)[idx]) : ldFlag(xin, idx, f);
            }
            v[ky][j] = val;
        }
    }
    float r[8], s[8], s2[8];
#pragma unroll
    for (int p = 0; p < 8; p++) {
        float a = bc;
#pragma unroll
        for (int ky = 0; ky < 3; ky++)
#pragma unroll
            for (int kx = 0; kx < 3; kx++) a += v[ky][p + kx] * wreg[ky * 3 + kx];
        r[p] = v[1][p + 1] + a;
        s[p] = r[p];
        s2[p] = r[p] * r[p];
    }
#pragma unroll
    for (int off = 32; off > 0; off >>= 1) {
#pragma unroll
        for (int p = 0; p < 8; p++) {
            s[p] += __shfl_down(s[p], off, 64);
            s2[p] += __shfl_down(s2[p], off, 64);
        }
    }
    __shared__ float shS[6][8], shS2[6][8];
    __shared__ float shMu[8], shRs[8];
    int wv = c >> 6, ln = c & 63;
    if (ln == 0) {
#pragma unroll
        for (int p = 0; p < 8; p++) {
            shS[wv][p] = s[p];
            shS2[wv][p] = s2[p];
        }
    }
    __syncthreads();
    if (c < 8) {
        float S = 0, S2 = 0;
#pragma unroll
        for (int q = 0; q < 6; q++) {
            S += shS[q][c];
            S2 += shS2[q][c];
        }
        float m = S * (1.0f / Cc);
        float var = S2 * (1.0f / Cc) - m * m;
        float rr = rsqrtf(var + EPSC);
        if (MODE == 0) {
            shMu[c] = m;
            shRs[c] = rr;
        } else {
            int row = b * Nn + hh * Ww + w0 + c;
            mu[row] = m;
            rs[row] = rr;
        }
    }
    if (MODE == 0) {
        __syncthreads();
        float gc = ldFlag(g, c, f), bbc = ldFlag(bb, c, f);
#pragma unroll
        for (int p = 0; p < 8; p++) {
            size_t oi = base + (size_t)(hh * Ww + w0 + p) * Cc + c;
            out[oi] = __float2bfloat16((r[p] - shMu[p]) * shRs[p] * gc + bbc);
        }
    } else {
#pragma unroll
        for (int p = 0; p < 8; p++) {
            size_t oi = base + (size_t)(hh * Ww + w0 + p) * Cc + c;
            out[oi] = __float2bfloat16(r[p]);
        }
    }
}

// ------- in-place split-K reduce: Gp[b][0] = sum_s Gp[b][s] (float4) -------
__global__ __launch_bounds__(256) void reduceG_k(float* __restrict__ Gp) {
    const size_t Q = (size_t)Cc * Cc / 4;  // 36864 float4 per matrix
    size_t j = (size_t)blockIdx.x * 256 + threadIdx.x;
    int b = (int)(j / Q);
    size_t i4 = j % Q;
    fx4* G4 = (fx4*)Gp;
    size_t base = (size_t)b * NS * Q;
    fx4 a = G4[base + i4];
#pragma unroll
    for (int s = 1; s < NS; s++) a += G4[base + (size_t)s * Q + i4];
    G4[base + i4] = a;
}

// ------- scalar tiled GEMM (kept for the small fp32 P = Gsum @ Wv step) -------
template <int AM, int OM, int WM, bool GELU, bool LNA, int RES, int AR>
__global__ __launch_bounds__(256) void gemm_k(const void* __restrict__ A, size_t aBatch,
                                              const void* __restrict__ W, size_t wBatch,
                                              int ldw, int colOff,
                                              const void* __restrict__ bias,
                                              const bf16* __restrict__ resid, size_t rBatch,
                                              const float* __restrict__ mu,
                                              const float* __restrict__ rs, size_t sBatch,
                                              const void* __restrict__ cg,
                                              const void* __restrict__ cb,
                                              void* __restrict__ out, size_t oBatch,
                                              size_t outRow0,
                                              int M, int K, int Nc,
                                              const int* __restrict__ flagp) {
    int f = *flagp;
    int z = blockIdx.z;
    const size_t MK = (size_t)M * K;
    __shared__ float As[16][68];
    __shared__ float Bs[16][68];
    int t = threadIdx.x;
    int tx = t & 15, ty = t >> 4;
    int row0 = blockIdx.x * 64, n0 = blockIdx.y * 64;
    float acc[4][4] = {};
    for (int k0 = 0; k0 < K; k0 += 16) {
#pragma unroll
        for (int i = 0; i < 4; i++) {
            int lin = i * 256 + t;
            int kk = lin & 15, m = lin >> 4;
            size_t ai = (size_t)z * aBatch + (size_t)(row0 + m) * K + k0 + kk;
            float v;
            if (AR > 1) {
                v = 0;
#pragma unroll
                for (int s = 0; s < AR; s++) v += ((const float*)A)[ai + (size_t)s * MK];
            } else {
                v = (AM == 0) ? ((const float*)A)[ai] : toF(((const bf16*)A)[ai]);
            }
            if (LNA) {
                float muv = mu[z * sBatch + row0 + m], rsv = rs[z * sBatch + row0 + m];
                v = (v - muv) * rsv * ldFlag(cg, k0 + kk, f) + ldFlag(cb, k0 + kk, f);
            }
            As[kk][m] = v;
        }
#pragma unroll
        for (int i = 0; i < 4; i++) {
            int lin = i * 256 + t;
            int nn2 = lin & 63, kk = lin >> 6;
            size_t wi = (size_t)z * wBatch + (size_t)(k0 + kk) * ldw + colOff + n0 + nn2;
            Bs[kk][nn2] = (WM == 1) ? toF(((const bf16*)W)[wi]) : ldFlag(W, wi, f);
        }
        __syncthreads();
#pragma unroll
        for (int kk = 0; kk < 16; kk++) {
            float a[4], bv[4];
#pragma unroll
            for (int i = 0; i < 4; i++) a[i] = As[kk][ty * 4 + i];
#pragma unroll
            for (int j = 0; j < 4; j++) bv[j] = Bs[kk][tx * 4 + j];
#pragma unroll
            for (int i = 0; i < 4; i++)
#pragma unroll
                for (int j = 0; j < 4; j++) acc[i][j] += a[i] * bv[j];
        }
        __syncthreads();
    }
#pragma unroll
    for (int i = 0; i < 4; i++) {
        int m = row0 + ty * 4 + i;
#pragma unroll
        for (int j = 0; j < 4; j++) {
            int nn2 = n0 + tx * 4 + j;
            float v = acc[i][j];
            if (bias) v += ldFlag(bias, nn2, f);
            if (GELU) v = 0.5f * v * (1.0f + erff(v * 0.70710678118654752f));
            if (RES == 1) v += toF(resid[(size_t)z * rBatch + (size_t)m * Nc + nn2]);
            size_t oi = (size_t)z * oBatch + (outRow0 + m) * (size_t)Nc + nn2;
            if (OM == 2) ((float*)out)[oi] = v;
            else if (OM == 1) ((bf16*)out)[oi] = __float2bfloat16(v);
            else {
                if (f) ((bf16*)out)[oi] = __float2bfloat16(v);
                else ((float*)out)[oi] = v;
            }
        }
    }
}

// ------- weight transpose + bf16 convert: WT[n][k] = W[k][n] -------
__global__ __launch_bounds__(256) void transpose_k(const void* __restrict__ W,
                                                   u16t* __restrict__ WT,
                                                   int K, int N,
                                                   const int* __restrict__ flagp) {
    int f = *flagp;
    __shared__ u16t T[64][72];
    int n0 = blockIdx.x * 64, k0 = blockIdx.y * 64;
    int t = threadIdx.x;
#pragma unroll
    for (int i = 0; i < 16; i++) {
        int lin = i * 256 + t;
        int kk = lin >> 6, nn = lin & 63;
        T[nn][kk] = f2u(ldFlag(W, (size_t)(k0 + kk) * N + n0 + nn, f));
    }
    __syncthreads();
#pragma unroll
    for (int i = 0; i < 16; i++) {
        int lin = i * 256 + t;
        int nn = lin >> 6, kk = lin & 63;
        WT[(size_t)(n0 + nn) * K + k0 + kk] = T[nn][kk];
    }
}

// ------- fc1T[n][k] = bf16(g[k] * fc1[k][n]) (LN gamma folded into weight) -------
__global__ __launch_bounds__(256) void transpose_scale_k(const void* __restrict__ W,
                                                         const void* __restrict__ g,
                                                         u16t* __restrict__ WT,
                                                         int K, int N,
                                                         const int* __restrict__ flagp) {
    int f = *flagp;
    __shared__ u16t T[64][72];
    int n0 = blockIdx.x * 64, k0 = blockIdx.y * 64;
    int t = threadIdx.x;
#pragma unroll
    for (int i = 0; i < 16; i++) {
        int lin = i * 256 + t;
        int kk = lin >> 6, nn = lin & 63;
        T[nn][kk] = f2u(ldFlag(g, k0 + kk, f) * ldFlag(W, (size_t)(k0 + kk) * N + n0 + nn, f));
    }
    __syncthreads();
#pragma unroll
    for (int i = 0; i < 16; i++) {
        int lin = i * 256 + t;
        int nn = lin >> 6, kk = lin & 63;
        WT[(size_t)(n0 + nn) * K + k0 + kk] = T[nn][kk];
    }
}

// ------- negc1[n] = -sum_k g[k]fc1[k,n]; cb2[n] = sum_k beta[k]fc1[k,n] + b1[n] -------
__global__ __launch_bounds__(256) void fc1fold_k(const void* __restrict__ fc1w,
                                                 const void* __restrict__ g,
                                                 const void* __restrict__ bb,
                                                 const void* __restrict__ b1,
                                                 float* __restrict__ negc1,
                                                 float* __restrict__ cb2,
                                                 const int* __restrict__ flagp) {
    int f = *flagp;
    __shared__ float gs[384], bs[384];
    int t = threadIdx.x;
    for (int i = t; i < 384; i += 256) {
        gs[i] = ldFlag(g, i, f);
        bs[i] = ldFlag(bb, i, f);
    }
    __syncthreads();
    int n = blockIdx.x * 256 + t;  // 0..1535
    float s1 = 0, s2 = 0;
    for (int k = 0; k < 384; k++) {
        float w = ldFlag(fc1w, (size_t)k * CH + n, f);
        s1 += gs[k] * w;
        s2 += bs[k] * w;
    }
    negc1[n] = -s1;
    cb2[n] = s2 + ldFlag(b1, n, f);
}

// ------- MFMA GEMM via global_load_lds staging (pre-swizzled per-lane source) -------
// 128x128 tile, 4 waves (2x2); [128][64] LDS, XOR chunk-swizzle (write side folded into
// per-lane global source address so LDS dest stays linear for global_load_lds).
// OM: 0 flag-dispatch out, 1 bf16 out. RES: 0 none, 1 bf16 resid, 2 add A[m][n] (K==N).
// EPI: 0 none, 1 fc1 LN-fold: v = rs[m]*(acc + mu[m]*negc1[n]) + cb2[n].
template <int OM, bool GELU, int RES, int EPI>
__global__ __launch_bounds__(256) void gemm_mfma(
    const u16t* __restrict__ A, size_t aBatch,
    const u16t* __restrict__ BT, size_t btBatch,
    const void* __restrict__ bias,
    const u16t* __restrict__ resid, size_t rBatch,
    const float* __restrict__ mu, const float* __restrict__ rs,
    const float* __restrict__ negc1, const float* __restrict__ cb2,
    void* __restrict__ out, size_t oBatch, size_t outRow0,
    int K, int N, const int* __restrict__ flagp) {
    int f = *flagp;
    int z = blockIdx.z;
    int t = threadIdx.x;
    int row0 = blockIdx.x * 128, n0 = blockIdx.y * 128;
    __shared__ u16t As[128][64];
    __shared__ u16t Bs[128][64];
    const u16t* Ab = A + (size_t)z * aBatch;
    const u16t* Bb = BT + (size_t)z * btBatch;
    int lane = t & 63, wv = t >> 6;
    // staging: wave wv covers rows 32wv..32wv+31 of both tiles, 4 strips of 8 rows.
    // lane l -> row srow=l>>3 within strip, physical chunk l&7 (lds linear),
    // global source chunk = (l&7)^srow  (so lds phys chunk p holds logical p^(row&7)).
    int srow = lane >> 3;
    int schk = ((lane & 7) ^ srow) << 3;
    const u16t* asrc[4];
    const u16t* bsrc[4];
    u16t* adst[4];
    u16t* bdst[4];
#pragma unroll
    for (int i = 0; i < 4; i++) {
        int r = 32 * wv + 8 * i;
        asrc[i] = Ab + (size_t)(row0 + r + srow) * K + schk;
        bsrc[i] = Bb + (size_t)(n0 + r + srow) * K + schk;
        adst[i] = &As[r][0];
        bdst[i] = &Bs[r][0];
    }
    fx4 acc[4][4];
    fx4 zz = {0.f, 0.f, 0.f, 0.f};
#pragma unroll
    for (int i = 0; i < 4; i++)
#pragma unroll
        for (int j = 0; j < 4; j++) acc[i][j] = zz;
    int wr = (wv >> 1) * 64, wc = (wv & 1) * 64;
    int lr = lane & 15, lg = lane >> 4;
    int KT = K / 64;
    for (int kt = 0; kt < KT; kt++) {
        if (kt) __syncthreads();  // prior compute done before overwrite
#pragma unroll
        for (int i = 0; i < 4; i++) {
            gload16(asrc[i] + kt * 64, adst[i]);
            gload16(bsrc[i] + kt * 64, bdst[i]);
        }
        __syncthreads();  // compiler drains vmcnt before barrier
#pragma unroll
        for (int ks = 0; ks < 2; ks++) {
            usx8 af[4], bfv[4];
#pragma unroll
            for (int r = 0; r < 4; r++) {
                int row = wr + r * 16 + lr;
                af[r] = *(const usx8*)&As[row][((4 * ks + lg) ^ (row & 7)) << 3];
            }
#pragma unroll
            for (int c = 0; c < 4; c++) {
                int row = wc + c * 16 + lr;
                bfv[c] = *(const usx8*)&Bs[row][((4 * ks + lg) ^ (row & 7)) << 3];
            }
#pragma unroll
            for (int r = 0; r < 4; r++)
#pragma unroll
                for (int c = 0; c < 4; c++)
                    acc[r][c] = mfma16(af[r], bfv[c], acc[r][c]);
        }
    }
#pragma unroll
    for (int r = 0; r < 4; r++) {
        int mb = row0 + wr + r * 16 + lg * 4;
        fx4 muq, rsq;
        if (EPI == 1) {
            muq = *(const fx4*)&mu[mb];
            rsq = *(const fx4*)&rs[mb];
        }
#pragma unroll
        for (int c = 0; c < 4; c++) {
            int gc = n0 + wc + c * 16 + lr;
            float bv = bias ? ldFlag(bias, gc, f) : 0.0f;
            float nc1 = (EPI == 1) ? negc1[gc] : 0.f;
            float cbv = (EPI == 1) ? cb2[gc] : 0.f;
#pragma unroll
            for (int q = 0; q < 4; q++) {
                int m = mb + q;
                float v;
                if (EPI == 1) v = rsq[q] * (acc[r][c][q] + muq[q] * nc1) + cbv;
                else v = acc[r][c][q] + bv;
                if (GELU) v = 0.5f * v * (1.0f + erff(v * 0.70710678118654752f));
                if (RES == 1) v += u2f(resid[(size_t)z * rBatch + (size_t)m * N + gc]);
                if (RES == 2) v += u2f(Ab[(size_t)m * K + gc]);
                size_t oi = (size_t)z * oBatch + (outRow0 + m) * (size_t)N + gc;
                if (OM == 1) ((u16t*)out)[oi] = f2u(v);
                else {
                    if (f) ((u16t*)out)[oi] = f2u(v);
                    else ((float*)out)[oi] = v;
                }
            }
        }
    }
}

// ------- MFMA gram split-K: Gp[b][sp] = lnS^T lnS over 1024 rows (lnS pre-normalized) -------
__global__ __launch_bounds__(256) void gram_mfma(const u16t* __restrict__ sc,
                                                 float* __restrict__ Gp) {
    int bx = blockIdx.x, sp = blockIdx.y, b = blockIdx.z;
    int ci0 = (bx / 3) * 128, cj0 = (bx % 3) * 128;
    __shared__ u16t As[128][72];
    __shared__ u16t Bs[128][72];
    int t = threadIdx.x;
    const int scc = (t * 8) & 127;  // fixed channel offset per thread
    const int snn = t >> 4;         // 0..15
    const int RPS = Nn / NS;        // 1024
    int rowbase = b * Nn + sp * RPS;
    usx8 ra[4], rb[4];
    auto ldstep = [&](int nn0) {
#pragma unroll
        for (int i = 0; i < 4; i++) {
            int r = rowbase + nn0 + i * 16 + snn;
            ra[i] = *(const usx8*)&sc[(size_t)r * Cc + ci0 + scc];
            rb[i] = *(const usx8*)&sc[(size_t)r * Cc + cj0 + scc];
        }
    };
    auto wrstep = [&]() {
#pragma unroll
        for (int i = 0; i < 4; i++) {
            int n = i * 16 + snn;
            int q = n >> 3, nl = n & 7;
#pragma unroll
            for (int j = 0; j < 8; j++) {
                int c = scc + j;
                int swz = ((c >> 3) ^ (c >> 6)) & 7;
                int po = ((q ^ swz) << 3) + nl;
                As[c][po] = ra[i][j];
                Bs[c][po] = rb[i][j];
            }
        }
    };
    fx4 acc[4][4];
    fx4 zz = {0.f, 0.f, 0.f, 0.f};
#pragma unroll
    for (int i = 0; i < 4; i++)
#pragma unroll
        for (int j = 0; j < 4; j++) acc[i][j] = zz;
    int lane = t & 63, w = t >> 6;
    int wr = (w >> 1) * 64, wc = (w & 1) * 64;
    int lr = lane & 15, lg = lane >> 4;
    ldstep(0);
    wrstep();
    __syncthreads();
    const int KT = RPS / 64;  // 16
    for (int kt = 0; kt < KT; kt++) {
        if (kt + 1 < KT) ldstep((kt + 1) * 64);
#pragma unroll
        for (int ks = 0; ks < 2; ks++) {
            usx8 af[4], bfv[4];
#pragma unroll
            for (int r = 0; r < 4; r++) {
                int ch = wr + r * 16 + lr;
                int swz = ((ch >> 3) ^ (ch >> 6)) & 7;
                af[r] = *(const usx8*)&As[ch][((ks * 4 + lg) ^ swz) << 3];
            }
#pragma unroll
            for (int c = 0; c < 4; c++) {
                int ch = wc + c * 16 + lr;
                int swz = ((ch >> 3) ^ (ch >> 6)) & 7;
                bfv[c] = *(const usx8*)&Bs[ch][((ks * 4 + lg) ^ swz) << 3];
            }
#pragma unroll
            for (int r = 0; r < 4; r++)
#pragma unroll
                for (int c = 0; c < 4; c++)
                    acc[r][c] = mfma16(af[r], bfv[c], acc[r][c]);
        }
        __syncthreads();
        if (kt + 1 < KT) {
            wrstep();
            __syncthreads();
        }
    }
    float* dst = Gp + ((size_t)b * NS + sp) * (size_t)Cc * Cc;
#pragma unroll
    for (int r = 0; r < 4; r++)
#pragma unroll
        for (int c = 0; c < 4; c++)
#pragma unroll
            for (int q = 0; q < 4; q++)
                dst[(size_t)(ci0 + wr + r * 16 + lg * 4 + q) * Cc + cj0 + wc + c * 16 + lr] =
                    acc[r][c][q];
}

// ------- S partials: Sp[b,h,sp] = Wk_h[c-range]^T @ P_b[c-range, h]. grid (NH, Bq, NSP). -------
__global__ __launch_bounds__(256) void attn_part_k(const float* __restrict__ P,
                                                   const void* __restrict__ kv_w,
                                                   float* __restrict__ Sp,
                                                   const int* __restrict__ flagp) {
    int f = *flagp;
    int hd = blockIdx.x;
    int b = blockIdx.y;
    int sp = blockIdx.z;
    int c0 = sp * 64;
    int t = threadIdx.x;
    const float* Pb = P + (size_t)b * Cc * Cc;
    __shared__ float Pc[64][49];
    __shared__ float Wkc[64][49];
    for (int idx = t; idx < 3072; idx += 256) {
        int r = idx / 48, e = idx % 48;
        int c = c0 + r;
        Pc[r][e] = Pb[(size_t)c * Cc + hd * 48 + e];
        Wkc[r][e] = ldFlag(kv_w, (size_t)c * 768 + hd * 48 + e, f);
    }
    __syncthreads();
    int obase = t * 9;
    float acc[9] = {};
#pragma unroll
    for (int r = 0; r < 64; r++) {
#pragma unroll
        for (int j = 0; j < 9; j++) {
            int d = (obase + j) / 48, e = (obase + j) % 48;
            acc[j] += Wkc[r][d] * Pc[r][e];
        }
    }
    float* dst = Sp + (((size_t)b * NH + hd) * NSP + sp) * 2304;
#pragma unroll
    for (int j = 0; j < 9; j++) dst[obase + j] = acc[j];
}

// ------- sum partials + softmax rows. grid (NH, Bq). -------
__global__ __launch_bounds__(256) void attn_soft_k(const float* __restrict__ Sp,
                                                   float* __restrict__ attn) {
    int hd = blockIdx.x;
    int b = blockIdx.y;
    int t = threadIdx.x;
    __shared__ float Ss[48][49];
    const float* src = Sp + (((size_t)b * NH + hd) * NSP) * 2304;
    for (int idx = t; idx < 2304; idx += 256) {
        float s = 0;
#pragma unroll
        for (int sp = 0; sp < NSP; sp++) s += src[sp * 2304 + idx];
        Ss[idx / 48][idx % 48] = s * SCALE;
    }
    __syncthreads();
    if (t < 48) {
        float m = -1e30f;
#pragma unroll
        for (int e = 0; e < 48; e++) m = fmaxf(m, Ss[t][e]);
        float ex[48];
        float sum = 0;
#pragma unroll
        for (int e = 0; e < 48; e++) {
            ex[e] = expf(Ss[t][e] - m);
            sum += ex[e];
        }
        float inv = 1.0f / sum;
#pragma unroll
        for (int e = 0; e < 48; e++)
            attn[((size_t)b * NH + hd) * 2304 + t * 48 + e] = ex[e] * inv;
    }
}

// ------- Wtilde[b][c][h*48+d] = sum_e Wq[c, h*48+e] * attn[b,h,d,e]. grid (6, NH, Bq). -------
__global__ __launch_bounds__(256) void wtilde_k(const void* __restrict__ q_w,
                                                const float* __restrict__ attn,
                                                bf16* __restrict__ Wt_,
                                                const int* __restrict__ flagp) {
    int f = *flagp;
    int c0 = blockIdx.x * 64;
    int hd = blockIdx.y;
    int b = blockIdx.z;
    int t = threadIdx.x;
    __shared__ float at[48][48];
    __shared__ float wq[64][48];
    const float* ab = attn + ((size_t)b * NH + hd) * 2304;
    for (int o = t; o < 2304; o += 256) at[o / 48][o % 48] = ab[o];
    for (int o = t; o < 3072; o += 256) {
        int cc = o / 48, e = o % 48;
        wq[cc][e] = ldFlag(q_w, (size_t)(c0 + cc) * Cc + hd * 48 + e, f);
    }
    __syncthreads();
    bf16* outb = Wt_ + (size_t)b * Cc * Cc;
    for (int o = t; o < 3072; o += 256) {
        int cc = o / 48, d = o % 48;
        float s = 0;
#pragma unroll
        for (int e = 0; e < 48; e++) s += wq[cc][e] * at[d][e];
        outb[(size_t)(c0 + cc) * Cc + hd * 48 + d] = __float2bfloat16(s);
    }
}

extern "C" void kernel_launch(void* const* d_in, const int* in_sizes, int n_in,
                              void* d_out, int out_size, void* d_ws, size_t ws_size,
                              hipStream_t stream) {
    (void)in_sizes; (void)n_in; (void)out_size;
    const void* x = d_in[0];
    const void* srcp = d_in[1];
    const void* cpe0_w = d_in[4];
    const void* cpe0_b = d_in[5];
    const void* cpe1_w = d_in[6];
    const void* cpe1_b = d_in[7];
    const void* n1g = d_in[8];
    const void* n1b = d_in[9];
    const void* q_w = d_in[10];
    const void* kv_w = d_in[11];
    const void* proj_w = d_in[12];
    const void* proj_b = d_in[13];
    const void* n2g = d_in[14];
    const void* n2b = d_in[15];
    const void* fc1_w = d_in[16];
    const void* fc1_b = d_in[17];
    const void* fc2_w = d_in[18];
    const void* fc2_b = d_in[19];
    char* ws = (char*)d_ws;

    // ---- workspace layout ----
    const size_t CcCc = (size_t)Cc * Cc;
    const size_t NnCc = (size_t)Nn * Cc;
    const size_t SLOT = (size_t)Mrows * Cc * sizeof(bf16);  // 25,165,824
    int* flag = (int*)ws;
    bf16* s0 = (bf16*)(ws + 64);            // lnS -> Sp (attn partials) -> x2 -> h1c
    bf16* s1 = (bf16*)(ws + 64 + SLOT);     // Gp (18.9MB fp32) -> WeffT (bf16) -> x3
    float* Gp = (float*)s1;
    u16t* WeffT = (u16t*)s1;                // [Bq][384(c_out)][384(c_in)] bf16
    bf16* x3 = s1;
    float* P = (float*)(ws + 64 + 2 * SLOT);        // 4,718,592 [Bq][384x384] fp32
    bf16* Wt_ = (bf16*)P;                           // alias (P dead after attn_part)
    u16t* projT = (u16t*)((char*)P + 2359296);      // [c_out][e] bf16
    u16t* fc1T = (u16t*)P;                          // [1536][384] bf16, after Weff gemm
    u16t* fc2T = (u16t*)((char*)P + 1179648);       // [384][1536] bf16
    float* attnB = (float*)(ws + 64 + 2 * SLOT + 4718592);  // 589,824
    float* mu2 = (float*)(ws + 64 + 2 * SLOT + 4718592 + 589824);
    float* rs2 = mu2 + Mrows;
    float* negc1 = rs2 + Mrows;  // [1536] fp32
    float* cb2 = negc1 + CH;     // [1536] fp32
    bf16* lnS = s0;
    float* Sp = (float*)s0;  // attn partials [Bq][NH][NSP][2304] fp32 = 3.5 MB (lnS dead)
    bf16* x2 = s0;
    u16t* h1c = (u16t*)s0;  // CR=8192 -> 25.17 MB, exact fit
    const size_t NEED = (size_t)((char*)(cb2 + CH) - ws);
    if (ws_size < NEED) return;

    bf16* lnX = (bf16*)d_out;  // d_out as bf16 scratch (dead before final writes)

    probe_k<<<1, 256, 0, stream>>>(x, flag);

    // 1. lnX = LN1(cpe0(x)) fused
    dwconv_ln<2, 0><<<dim3(Ww / 8, Hh, Bq), 384, 0, stream>>>(
        x, cpe0_w, cpe0_b, lnX, n1g, n1b, nullptr, nullptr, flag);

    // 2. lnS = LN1(cpe0(source)) fused -> MFMA gram partials -> in-place reduce
    dwconv_ln<2, 0><<<dim3(Ww / 8, Hh, Bq), 384, 0, stream>>>(
        srcp, cpe0_w, cpe0_b, lnS, n1g, n1b, nullptr, nullptr, flag);
    gram_mfma<<<dim3(9, NS, Bq), 256, 0, stream>>>((const u16t*)lnS, Gp);
    reduceG_k<<<(Bq * CcCc / 4) / 256, 256, 0, stream>>>(Gp);

    // 3. P_b = Gsum_b @ Wv   (fp32 scalar; Wv = kv_w cols 384..767)
    gemm_k<0, 2, 2, false, false, 0, 1><<<dim3(6, 6, Bq), 256, 0, stream>>>(
        Gp, (size_t)NS * CcCc, kv_w, 0, 768, 384, nullptr, nullptr, 0,
        nullptr, nullptr, 0, nullptr, nullptr, P, CcCc, 0, Cc, Cc, Cc, flag);

    // 4. attn: split-c partials (into dead s0) -> softmax -> fold into WeffT
    attn_part_k<<<dim3(NH, Bq, NSP), 256, 0, stream>>>(P, kv_w, Sp, flag);
    attn_soft_k<<<dim3(NH, Bq), 256, 0, stream>>>(Sp, attnB);
    wtilde_k<<<dim3(6, NH, Bq), 256, 0, stream>>>(q_w, attnB, Wt_, flag);
    transpose_k<<<dim3(6, 6), 256, 0, stream>>>(proj_w, projT, Cc, Cc, flag);
    gemm_mfma<1, false, 0, 0><<<dim3(3, 3, Bq), 256, 0, stream>>>(
        projT, 0, (const u16t*)Wt_, CcCc, nullptr, nullptr, 0,
        nullptr, nullptr, nullptr, nullptr, WeffT, CcCc, 0, Cc, Cc, flag);

    // MLP weight prep (P region free of Wt_ after Weff gemm; stream-ordered)
    transpose_scale_k<<<dim3(24, 6), 256, 0, stream>>>(fc1_w, n2g, fc1T, Cc, CH, flag);
    transpose_k<<<dim3(6, 24), 256, 0, stream>>>(fc2_w, fc2T, CH, Cc, flag);
    fc1fold_k<<<CH / 256, 256, 0, stream>>>(fc1_w, n2g, n2b, fc1_b, negc1, cb2, flag);

    // 5. x2 = lnX + lnX @ Weff_b + proj_b   (plain MFMA, RES=2 adds A element)
    gemm_mfma<1, false, 2, 0><<<dim3(32, 3, Bq), 256, 0, stream>>>(
        (const u16t*)lnX, NnCc, WeffT, CcCc, proj_b, nullptr, 0,
        nullptr, nullptr, nullptr, nullptr, x2, NnCc, 0, Cc, Cc, flag);

    // 6. x3 = cpe1(x2) raw + LN2 stats (fused)
    dwconv_ln<1, 1><<<dim3(Ww / 8, Hh, Bq), 384, 0, stream>>>(
        x2, cpe1_w, cpe1_b, x3, nullptr, nullptr, mu2, rs2, flag);

    // 7. MLP in 8192-row chunks: out = x3 + gelu(LN2(x3)@fc1+b1)@fc2+b2
    //    fc1 = plain GEMM on raw x3 with LN folded: gelu(rs*(x3@(g.fc1) + mu*negc1) + cb2)
    constexpr int CR = 8192;
    for (int ch = 0; ch < Mrows / CR; ch++) {
        size_t roff = (size_t)ch * CR;
        gemm_mfma<1, true, 0, 1><<<dim3(CR / 128, CH / 128, 1), 256, 0, stream>>>(
            (const u16t*)x3 + roff * Cc, 0, fc1T, 0, nullptr, nullptr, 0,
            mu2 + roff, rs2 + roff, negc1, cb2, h1c, 0, 0, Cc, CH, flag);
        gemm_mfma<0, false, 1, 0><<<dim3(CR / 128, Cc / 128, 1), 256, 0, stream>>>(
            h1c, 0, fc2T, 0, fc2_b, (const u16t*)x3 + roff * Cc, 0,
            nullptr, nullptr, nullptr, nullptr, d_out, 0, roff, CH, Cc, flag);
    }
}

// Round 6
// 773.796 us; speedup vs baseline: 1.1461x; 1.0357x over previous
//
#include <hip/hip_runtime.h>
#include <hip/hip_bf16.h>
#include <math.h>

typedef __hip_bfloat16 bf16;
typedef unsigned short u16t;
typedef __bf16 bfx8 __attribute__((ext_vector_type(8)));
typedef float fx4 __attribute__((ext_vector_type(4)));
typedef unsigned short usx8 __attribute__((ext_vector_type(8)));

constexpr int Bq = 8, Hh = 64, Ww = 64, Nn = 4096, Cc = 384, NH = 8, CH = 1536;
constexpr int Mrows = Bq * Nn;  // 32768
constexpr int NS = 4;           // gram split-K factor
constexpr int NSP = 6;          // attn S split-c factor
constexpr float EPSC = 1e-5f;
constexpr float SCALE = 0.14433756729740643f;  // 48^-0.5

__device__ __forceinline__ float toF(bf16 v) { return __bfloat162float(v); }

__device__ __forceinline__ float ldFlag(const void* p, size_t i, int f) {
    if (f) return __bfloat162float(((const bf16*)p)[i]);
    return ((const float*)p)[i];
}

__device__ __forceinline__ float u2f(u16t u) {
    unsigned int x = ((unsigned int)u) << 16;
    float fv;
    __builtin_memcpy(&fv, &x, 4);
    return fv;
}
__device__ __forceinline__ u16t f2u(float v) {
    bf16 h = __float2bfloat16(v);
    u16t u;
    __builtin_memcpy(&u, &h, 2);
    return u;
}
__device__ __forceinline__ fx4 mfma16(usx8 a, usx8 b, fx4 c) {
    return __builtin_amdgcn_mfma_f32_16x16x32_bf16(
        __builtin_bit_cast(bfx8, a), __builtin_bit_cast(bfx8, b), c, 0, 0, 0);
}

// async global->LDS 16B copy; lds dest is wave-uniform base + lane*16
__device__ __forceinline__ void gload16(const void* g, void* l) {
    __builtin_amdgcn_global_load_lds(
        reinterpret_cast<const __attribute__((address_space(1))) unsigned int*>(
            reinterpret_cast<uintptr_t>(g)),
        reinterpret_cast<__attribute__((address_space(3))) unsigned int*>(
            reinterpret_cast<uintptr_t>(l)),
        16, 0, 0);
}

// ---- probe: bf16 N(0,1) data never has exponent>=134 (|v|>=128); fp32 halves do. ----
__global__ __launch_bounds__(256) void probe_k(const void* __restrict__ p, int* __restrict__ flag) {
    int t = threadIdx.x;
    int bad = 0;
    for (int i = t; i < 4096; i += 256) {
        unsigned short u = ((const unsigned short*)p)[i];
        unsigned e = (u >> 7) & 0xFF;
        if (e >= 134) bad++;
    }
    __shared__ int sh[256];
    sh[t] = bad;
    __syncthreads();
    for (int s = 128; s > 0; s >>= 1) {
        if (t < s) sh[t] += sh[t + s];
        __syncthreads();
    }
    if (t == 0) flag[0] = (sh[0] < 64) ? 1 : 0;  // 1 = bf16, 0 = fp32
}

// ---- fused depthwise 3x3 conv + bias + residual (+LN normalize OR +stats) ----
template <int INM, int MODE>
__global__ __launch_bounds__(384) void dwconv_ln(const void* __restrict__ xin,
                                                 const void* __restrict__ w,
                                                 const void* __restrict__ bias,
                                                 bf16* __restrict__ out,
                                                 const void* __restrict__ g,
                                                 const void* __restrict__ bb,
                                                 float* __restrict__ mu,
                                                 float* __restrict__ rs,
                                                 const int* __restrict__ flagp) {
    int f = *flagp;
    int c = threadIdx.x;      // channel 0..383
    int w0 = blockIdx.x * 8;  // 0..56
    int hh = blockIdx.y;
    int b = blockIdx.z;
    size_t base = (size_t)b * Nn * Cc;
    float wreg[9];
#pragma unroll
    for (int j = 0; j < 9; j++) wreg[j] = ldFlag(w, c * 9 + j, f);
    float bc = ldFlag(bias, c, f);
    float v[3][10];
#pragma unroll
    for (int ky = 0; ky < 3; ky++) {
        int yy = hh + ky - 1;
        bool rv = (yy >= 0 && yy < Hh);
#pragma unroll
        for (int j = 0; j < 10; j++) {
            int xx = w0 - 1 + j;
            bool cv = (xx >= 0 && xx < Ww);
            float val = 0.f;
            if (rv && cv) {
                size_t idx = base + (size_t)(yy * Ww + xx) * Cc + c;
                val = (INM == 1) ? toF(((const bf16*)xin)[idx]) : ldFlag(xin, idx, f);
            }
            v[ky][j] = val;
        }
    }
    float r[8], s[8], s2[8];
#pragma unroll
    for (int p = 0; p < 8; p++) {
        float a = bc;
#pragma unroll
        for (int ky = 0; ky < 3; ky++)
#pragma unroll
            for (int kx = 0; kx < 3; kx++) a += v[ky][p + kx] * wreg[ky * 3 + kx];
        r[p] = v[1][p + 1] + a;
        s[p] = r[p];
        s2[p] = r[p] * r[p];
    }
#pragma unroll
    for (int off = 32; off > 0; off >>= 1) {
#pragma unroll
        for (int p = 0; p < 8; p++) {
            s[p] += __shfl_down(s[p], off, 64);
            s2[p] += __shfl_down(s2[p], off, 64);
        }
    }
    __shared__ float shS[6][8], shS2[6][8];
    __shared__ float shMu[8], shRs[8];
    int wv = c >> 6, ln = c & 63;
    if (ln == 0) {
#pragma unroll
        for (int p = 0; p < 8; p++) {
            shS[wv][p] = s[p];
            shS2[wv][p] = s2[p];
        }
    }
    __syncthreads();
    if (c < 8) {
        float S = 0, S2 = 0;
#pragma unroll
        for (int q = 0; q < 6; q++) {
            S += shS[q][c];
            S2 += shS2[q][c];
        }
        float m = S * (1.0f / Cc);
        float var = S2 * (1.0f / Cc) - m * m;
        float rr = rsqrtf(var + EPSC);
        if (MODE == 0) {
            shMu[c] = m;
            shRs[c] = rr;
        } else {
            int row = b * Nn + hh * Ww + w0 + c;
            mu[row] = m;
            rs[row] = rr;
        }
    }
    if (MODE == 0) {
        __syncthreads();
        float gc = ldFlag(g, c, f), bbc = ldFlag(bb, c, f);
#pragma unroll
        for (int p = 0; p < 8; p++) {
            size_t oi = base + (size_t)(hh * Ww + w0 + p) * Cc + c;
            out[oi] = __float2bfloat16((r[p] - shMu[p]) * shRs[p] * gc + bbc);
        }
    } else {
#pragma unroll
        for (int p = 0; p < 8; p++) {
            size_t oi = base + (size_t)(hh * Ww + w0 + p) * Cc + c;
            out[oi] = __float2bfloat16(r[p]);
        }
    }
}

// ------- split-K reduce + hi/lo bf16 split: Gs[b][m][0:384]=hi, [384:768]=lo -------
__global__ __launch_bounds__(256) void reduceG_k(const float* __restrict__ Gp,
                                                 u16t* __restrict__ Gs) {
    const size_t Q4 = (size_t)Cc * Cc / 4;  // 36864 float4 per matrix
    size_t j = (size_t)blockIdx.x * 256 + threadIdx.x;
    int b = (int)(j / Q4);
    size_t i4 = j % Q4;
    const fx4* G4 = (const fx4*)Gp;
    size_t base = (size_t)b * NS * Q4;
    fx4 a = G4[base + i4];
#pragma unroll
    for (int s = 1; s < NS; s++) a += G4[base + (size_t)s * Q4 + i4];
    int e0 = (int)(i4 * 4);
    int m = e0 / Cc, k = e0 % Cc;
    u16t* row = Gs + ((size_t)b * Cc + m) * 768 + k;
#pragma unroll
    for (int q = 0; q < 4; q++) {
        u16t hi = f2u(a[q]);
        row[q] = hi;
        row[384 + q] = f2u(a[q] - u2f(hi));
    }
}

// ------- weight transpose + bf16 convert: WT[n][dstStride] <- W[k][ldw] -------
__global__ __launch_bounds__(256) void transpose_k(const void* __restrict__ W,
                                                   u16t* __restrict__ WT,
                                                   int ldw, int colOff,
                                                   int dstStride, int dstOff,
                                                   const int* __restrict__ flagp) {
    int f = *flagp;
    __shared__ u16t T[64][72];
    int n0 = blockIdx.x * 64, k0 = blockIdx.y * 64;
    int t = threadIdx.x;
#pragma unroll
    for (int i = 0; i < 16; i++) {
        int lin = i * 256 + t;
        int kk = lin >> 6, nn = lin & 63;
        T[nn][kk] = f2u(ldFlag(W, (size_t)(k0 + kk) * ldw + colOff + n0 + nn, f));
    }
    __syncthreads();
#pragma unroll
    for (int i = 0; i < 16; i++) {
        int lin = i * 256 + t;
        int nn = lin >> 6, kk = lin & 63;
        WT[(size_t)(n0 + nn) * dstStride + dstOff + k0 + kk] = T[nn][kk];
    }
}

// ------- fc1T[n][k] = bf16(g[k] * fc1[k][n]) (LN gamma folded into weight) -------
__global__ __launch_bounds__(256) void transpose_scale_k(const void* __restrict__ W,
                                                         const void* __restrict__ g,
                                                         u16t* __restrict__ WT,
                                                         int K, int N,
                                                         const int* __restrict__ flagp) {
    int f = *flagp;
    __shared__ u16t T[64][72];
    int n0 = blockIdx.x * 64, k0 = blockIdx.y * 64;
    int t = threadIdx.x;
#pragma unroll
    for (int i = 0; i < 16; i++) {
        int lin = i * 256 + t;
        int kk = lin >> 6, nn = lin & 63;
        T[nn][kk] = f2u(ldFlag(g, k0 + kk, f) * ldFlag(W, (size_t)(k0 + kk) * N + n0 + nn, f));
    }
    __syncthreads();
#pragma unroll
    for (int i = 0; i < 16; i++) {
        int lin = i * 256 + t;
        int nn = lin >> 6, kk = lin & 63;
        WT[(size_t)(n0 + nn) * K + k0 + kk] = T[nn][kk];
    }
}

// ------- negc1[n] = -sum_k g[k]fc1[k,n]; cb2[n] = sum_k beta[k]fc1[k,n] + b1[n] -------
__global__ __launch_bounds__(256) void fc1fold_k(const void* __restrict__ fc1w,
                                                 const void* __restrict__ g,
                                                 const void* __restrict__ bb,
                                                 const void* __restrict__ b1,
                                                 float* __restrict__ negc1,
                                                 float* __restrict__ cb2,
                                                 const int* __restrict__ flagp) {
    int f = *flagp;
    __shared__ float gs[384], bs[384];
    int t = threadIdx.x;
    for (int i = t; i < 384; i += 256) {
        gs[i] = ldFlag(g, i, f);
        bs[i] = ldFlag(bb, i, f);
    }
    __syncthreads();
    int n = blockIdx.x * 256 + t;  // 0..1535
    float s1 = 0, s2 = 0;
    for (int k = 0; k < 384; k++) {
        float w = ldFlag(fc1w, (size_t)k * CH + n, f);
        s1 += gs[k] * w;
        s2 += bs[k] * w;
    }
    negc1[n] = -s1;
    cb2[n] = s2 + ldFlag(b1, n, f);
}

// ------- MFMA GEMM, double-buffered global_load_lds staging (pre-swizzled source) ----
// 128x128 tile, 4 waves (2x2); 2x [128][64] LDS per operand, XOR chunk-swizzle folded
// into the per-lane global source address (LDS dest linear for global_load_lds).
// OM: 0 flag-dispatch out, 1 bf16 out, 2 fp32 out.
// RES: 0 none, 1 bf16 resid, 2 add A[m][n] (K==N).
// EPI: 0 none, 1 fc1 LN-fold: v = rs[m]*(acc + mu[m]*negc1[n]) + cb2[n].
template <int OM, bool GELU, int RES, int EPI>
__global__ __launch_bounds__(256) void gemm_mfma(
    const u16t* __restrict__ A, size_t aBatch,
    const u16t* __restrict__ BT, size_t btBatch,
    const void* __restrict__ bias,
    const u16t* __restrict__ resid, size_t rBatch,
    const float* __restrict__ mu, const float* __restrict__ rs,
    const float* __restrict__ negc1, const float* __restrict__ cb2,
    void* __restrict__ out, size_t oBatch, size_t outRow0,
    int K, int N, const int* __restrict__ flagp) {
    int f = *flagp;
    int z = blockIdx.z;
    int t = threadIdx.x;
    int row0 = blockIdx.x * 128, n0 = blockIdx.y * 128;
    __shared__ u16t As[2][128][64];
    __shared__ u16t Bs[2][128][64];
    const u16t* Ab = A + (size_t)z * aBatch;
    const u16t* Bb = BT + (size_t)z * btBatch;
    int lane = t & 63, wv = t >> 6;
    // staging: wave wv covers rows 32wv..32wv+31, 4 strips of 8 rows.
    // lane l -> row srow=l>>3 in strip, phys chunk l&7 (linear), global chunk (l&7)^srow.
    int srow = lane >> 3;
    int schk = ((lane & 7) ^ srow) << 3;
    const u16t* asrc[4];
    const u16t* bsrc[4];
    int rbase[4];
#pragma unroll
    for (int i = 0; i < 4; i++) {
        int r = 32 * wv + 8 * i;
        rbase[i] = r;
        asrc[i] = Ab + (size_t)(row0 + r + srow) * K + schk;
        bsrc[i] = Bb + (size_t)(n0 + r + srow) * K + schk;
    }
    auto STAGE = [&](int kt, int buf) {
#pragma unroll
        for (int i = 0; i < 4; i++) {
            gload16(asrc[i] + kt * 64, &As[buf][rbase[i]][0]);
            gload16(bsrc[i] + kt * 64, &Bs[buf][rbase[i]][0]);
        }
    };
    fx4 acc[4][4];
    fx4 zz = {0.f, 0.f, 0.f, 0.f};
#pragma unroll
    for (int i = 0; i < 4; i++)
#pragma unroll
        for (int j = 0; j < 4; j++) acc[i][j] = zz;
    int wr = (wv >> 1) * 64, wc = (wv & 1) * 64;
    int lr = lane & 15, lg = lane >> 4;
    int KT = K / 64;
    STAGE(0, 0);
    __syncthreads();
    for (int kt = 0; kt < KT; kt++) {
        int cur = kt & 1;
        if (kt + 1 < KT) STAGE(kt + 1, cur ^ 1);  // prefetch overlaps MFMA below
#pragma unroll
        for (int ks = 0; ks < 2; ks++) {
            usx8 af[4], bfv[4];
#pragma unroll
            for (int r = 0; r < 4; r++) {
                int row = wr + r * 16 + lr;
                af[r] = *(const usx8*)&As[cur][row][((4 * ks + lg) ^ (row & 7)) << 3];
            }
#pragma unroll
            for (int c = 0; c < 4; c++) {
                int row = wc + c * 16 + lr;
                bfv[c] = *(const usx8*)&Bs[cur][row][((4 * ks + lg) ^ (row & 7)) << 3];
            }
#pragma unroll
            for (int r = 0; r < 4; r++)
#pragma unroll
                for (int c = 0; c < 4; c++)
                    acc[r][c] = mfma16(af[r], bfv[c], acc[r][c]);
        }
        __syncthreads();  // drains prefetch vmcnt + guards buffer reuse
    }
#pragma unroll
    for (int r = 0; r < 4; r++) {
        int mb = row0 + wr + r * 16 + lg * 4;
        fx4 muq, rsq;
        if (EPI == 1) {
            muq = *(const fx4*)&mu[mb];
            rsq = *(const fx4*)&rs[mb];
        }
#pragma unroll
        for (int c = 0; c < 4; c++) {
            int gc = n0 + wc + c * 16 + lr;
            float bv = bias ? ldFlag(bias, gc, f) : 0.0f;
            float nc1 = (EPI == 1) ? negc1[gc] : 0.f;
            float cbv = (EPI == 1) ? cb2[gc] : 0.f;
#pragma unroll
            for (int q = 0; q < 4; q++) {
                int m = mb + q;
                float v;
                if (EPI == 1) v = rsq[q] * (acc[r][c][q] + muq[q] * nc1) + cbv;
                else v = acc[r][c][q] + bv;
                if (GELU) v = 0.5f * v * (1.0f + erff(v * 0.70710678118654752f));
                if (RES == 1) v += u2f(resid[(size_t)z * rBatch + (size_t)m * N + gc]);
                if (RES == 2) v += u2f(Ab[(size_t)m * K + gc]);
                size_t oi = (size_t)z * oBatch + (outRow0 + m) * (size_t)N + gc;
                if (OM == 1) ((u16t*)out)[oi] = f2u(v);
                else if (OM == 2) ((float*)out)[oi] = v;
                else {
                    if (f) ((u16t*)out)[oi] = f2u(v);
                    else ((float*)out)[oi] = v;
                }
            }
        }
    }
}

// ------- MFMA gram split-K: Gp[b][sp] = lnS^T lnS over 1024 rows (lnS pre-normalized) -------
__global__ __launch_bounds__(256) void gram_mfma(const u16t* __restrict__ sc,
                                                 float* __restrict__ Gp) {
    int bx = blockIdx.x, sp = blockIdx.y, b = blockIdx.z;
    int ci0 = (bx / 3) * 128, cj0 = (bx % 3) * 128;
    __shared__ u16t As[128][72];
    __shared__ u16t Bs[128][72];
    int t = threadIdx.x;
    const int scc = (t * 8) & 127;  // fixed channel offset per thread
    const int snn = t >> 4;         // 0..15
    const int RPS = Nn / NS;        // 1024
    int rowbase = b * Nn + sp * RPS;
    usx8 ra[4], rb[4];
    auto ldstep = [&](int nn0) {
#pragma unroll
        for (int i = 0; i < 4; i++) {
            int r = rowbase + nn0 + i * 16 + snn;
            ra[i] = *(const usx8*)&sc[(size_t)r * Cc + ci0 + scc];
            rb[i] = *(const usx8*)&sc[(size_t)r * Cc + cj0 + scc];
        }
    };
    auto wrstep = [&]() {
#pragma unroll
        for (int i = 0; i < 4; i++) {
            int n = i * 16 + snn;
            int q = n >> 3, nl = n & 7;
#pragma unroll
            for (int j = 0; j < 8; j++) {
                int c = scc + j;
                int swz = ((c >> 3) ^ (c >> 6)) & 7;
                int po = ((q ^ swz) << 3) + nl;
                As[c][po] = ra[i][j];
                Bs[c][po] = rb[i][j];
            }
        }
    };
    fx4 acc[4][4];
    fx4 zz = {0.f, 0.f, 0.f, 0.f};
#pragma unroll
    for (int i = 0; i < 4; i++)
#pragma unroll
        for (int j = 0; j < 4; j++) acc[i][j] = zz;
    int lane = t & 63, w = t >> 6;
    int wr = (w >> 1) * 64, wc = (w & 1) * 64;
    int lr = lane & 15, lg = lane >> 4;
    ldstep(0);
    wrstep();
    __syncthreads();
    const int KT = RPS / 64;  // 16
    for (int kt = 0; kt < KT; kt++) {
        if (kt + 1 < KT) ldstep((kt + 1) * 64);
#pragma unroll
        for (int ks = 0; ks < 2; ks++) {
            usx8 af[4], bfv[4];
#pragma unroll
            for (int r = 0; r < 4; r++) {
                int ch = wr + r * 16 + lr;
                int swz = ((ch >> 3) ^ (ch >> 6)) & 7;
                af[r] = *(const usx8*)&As[ch][((ks * 4 + lg) ^ swz) << 3];
            }
#pragma unroll
            for (int c = 0; c < 4; c++) {
                int ch = wc + c * 16 + lr;
                int swz = ((ch >> 3) ^ (ch >> 6)) & 7;
                bfv[c] = *(const usx8*)&Bs[ch][((ks * 4 + lg) ^ swz) << 3];
            }
#pragma unroll
            for (int r = 0; r < 4; r++)
#pragma unroll
                for (int c = 0; c < 4; c++)
                    acc[r][c] = mfma16(af[r], bfv[c], acc[r][c]);
        }
        __syncthreads();
        if (kt + 1 < KT) {
            wrstep();
            __syncthreads();
        }
    }
    float* dst = Gp + ((size_t)b * NS + sp) * (size_t)Cc * Cc;
#pragma unroll
    for (int r = 0; r < 4; r++)
#pragma unroll
        for (int c = 0; c < 4; c++)
#pragma unroll
            for (int q = 0; q < 4; q++)
                dst[(size_t)(ci0 + wr + r * 16 + lg * 4 + q) * Cc + cj0 + wc + c * 16 + lr] =
                    acc[r][c][q];
}

// ------- S partials: Sp[b,h,sp] = Wk_h[c-range]^T @ P_b[c-range, h]. grid (NH, Bq, NSP). -------
__global__ __launch_bounds__(256) void attn_part_k(const float* __restrict__ P,
                                                   const void* __restrict__ kv_w,
                                                   float* __restrict__ Sp,
                                                   const int* __restrict__ flagp) {
    int f = *flagp;
    int hd = blockIdx.x;
    int b = blockIdx.y;
    int sp = blockIdx.z;
    int c0 = sp * 64;
    int t = threadIdx.x;
    const float* Pb = P + (size_t)b * Cc * Cc;
    __shared__ float Pc[64][49];
    __shared__ float Wkc[64][49];
    for (int idx = t; idx < 3072; idx += 256) {
        int r = idx / 48, e = idx % 48;
        int c = c0 + r;
        Pc[r][e] = Pb[(size_t)c * Cc + hd * 48 + e];
        Wkc[r][e] = ldFlag(kv_w, (size_t)c * 768 + hd * 48 + e, f);
    }
    __syncthreads();
    int obase = t * 9;
    float acc[9] = {};
#pragma unroll
    for (int r = 0; r < 64; r++) {
#pragma unroll
        for (int j = 0; j < 9; j++) {
            int d = (obase + j) / 48, e = (obase + j) % 48;
            acc[j] += Wkc[r][d] * Pc[r][e];
        }
    }
    float* dst = Sp + (((size_t)b * NH + hd) * NSP + sp) * 2304;
#pragma unroll
    for (int j = 0; j < 9; j++) dst[obase + j] = acc[j];
}

// ------- sum partials + softmax rows. grid (NH, Bq). -------
__global__ __launch_bounds__(256) void attn_soft_k(const float* __restrict__ Sp,
                                                   float* __restrict__ attn) {
    int hd = blockIdx.x;
    int b = blockIdx.y;
    int t = threadIdx.x;
    __shared__ float Ss[48][49];
    const float* src = Sp + (((size_t)b * NH + hd) * NSP) * 2304;
    for (int idx = t; idx < 2304; idx += 256) {
        float s = 0;
#pragma unroll
        for (int sp = 0; sp < NSP; sp++) s += src[sp * 2304 + idx];
        Ss[idx / 48][idx % 48] = s * SCALE;
    }
    __syncthreads();
    if (t < 48) {
        float m = -1e30f;
#pragma unroll
        for (int e = 0; e < 48; e++) m = fmaxf(m, Ss[t][e]);
        float ex[48];
        float sum = 0;
#pragma unroll
        for (int e = 0; e < 48; e++) {
            ex[e] = expf(Ss[t][e] - m);
            sum += ex[e];
        }
        float inv = 1.0f / sum;
#pragma unroll
        for (int e = 0; e < 48; e++)
            attn[((size_t)b * NH + hd) * 2304 + t * 48 + e] = ex[e] * inv;
    }
}

// ------- Wtilde[b][c][h*48+d] = sum_e Wq[c, h*48+e] * attn[b,h,d,e]. grid (6, NH, Bq). -------
__global__ __launch_bounds__(256) void wtilde_k(const void* __restrict__ q_w,
                                                const float* __restrict__ attn,
                                                bf16* __restrict__ Wt_,
                                                const int* __restrict__ flagp) {
    int f = *flagp;
    int c0 = blockIdx.x * 64;
    int hd = blockIdx.y;
    int b = blockIdx.z;
    int t = threadIdx.x;
    __shared__ float at[48][48];
    __shared__ float wq[64][48];
    const float* ab = attn + ((size_t)b * NH + hd) * 2304;
    for (int o = t; o < 2304; o += 256) at[o / 48][o % 48] = ab[o];
    for (int o = t; o < 3072; o += 256) {
        int cc = o / 48, e = o % 48;
        wq[cc][e] = ldFlag(q_w, (size_t)(c0 + cc) * Cc + hd * 48 + e, f);
    }
    __syncthreads();
    bf16* outb = Wt_ + (size_t)b * Cc * Cc;
    for (int o = t; o < 3072; o += 256) {
        int cc = o / 48, d = o % 48;
        float s = 0;
#pragma unroll
        for (int e = 0; e < 48; e++) s += wq[cc][e] * at[d][e];
        outb[(size_t)(c0 + cc) * Cc + hd * 48 + d] = __float2bfloat16(s);
    }
}

extern "C" void kernel_launch(void* const* d_in, const int* in_sizes, int n_in,
                              void* d_out, int out_size, void* d_ws, size_t ws_size,
                              hipStream_t stream) {
    (void)in_sizes; (void)n_in; (void)out_size;
    const void* x = d_in[0];
    const void* srcp = d_in[1];
    const void* cpe0_w = d_in[4];
    const void* cpe0_b = d_in[5];
    const void* cpe1_w = d_in[6];
    const void* cpe1_b = d_in[7];
    const void* n1g = d_in[8];
    const void* n1b = d_in[9];
    const void* q_w = d_in[10];
    const void* kv_w = d_in[11];
    const void* proj_w = d_in[12];
    const void* proj_b = d_in[13];
    const void* n2g = d_in[14];
    const void* n2b = d_in[15];
    const void* fc1_w = d_in[16];
    const void* fc1_b = d_in[17];
    const void* fc2_w = d_in[18];
    const void* fc2_b = d_in[19];
    char* ws = (char*)d_ws;

    // ---- workspace layout ----
    const size_t CcCc = (size_t)Cc * Cc;
    const size_t NnCc = (size_t)Nn * Cc;
    const size_t SLOT = (size_t)Mrows * Cc * sizeof(bf16);  // 25,165,824
    int* flag = (int*)ws;
    bf16* s0 = (bf16*)(ws + 64);            // lnS -> Sp (attn partials) -> x2 -> h1c
    bf16* s1 = (bf16*)(ws + 64 + SLOT);     // Gp (18.9MB) + Gsplit (4.7MB) -> WeffT -> x3
    float* Gp = (float*)s1;
    u16t* Gsplit = (u16t*)((char*)s1 + 18874368);  // [Bq][384][768] bf16 hi|lo, 4.7MB
    u16t* WeffT = (u16t*)s1;                // [Bq][384(c_out)][384(c_in)] bf16
    bf16* x3 = s1;
    float* P = (float*)(ws + 64 + 2 * SLOT);        // 4,718,592 [Bq][384x384] fp32
    bf16* Wt_ = (bf16*)P;                           // alias (P dead after attn_part)
    u16t* projT = (u16t*)((char*)P + 2359296);      // [c_out][e] bf16
    u16t* fc1T = (u16t*)P;                          // [1536][384] bf16, after Weff gemm
    u16t* fc2T = (u16t*)((char*)P + 1179648);       // [384][1536] bf16
    float* attnB = (float*)(ws + 64 + 2 * SLOT + 4718592);  // 589,824
    u16t* WvT768 = (u16t*)attnB;  // [384][768] bf16 (dead before attn_soft writes attnB)
    float* mu2 = (float*)(ws + 64 + 2 * SLOT + 4718592 + 589824);
    float* rs2 = mu2 + Mrows;
    float* negc1 = rs2 + Mrows;  // [1536] fp32
    float* cb2 = negc1 + CH;     // [1536] fp32
    bf16* lnS = s0;
    float* Sp = (float*)s0;  // attn partials [Bq][NH][NSP][2304] fp32 = 3.5 MB (lnS dead)
    bf16* x2 = s0;
    u16t* h1c = (u16t*)s0;  // CR=8192 -> 25.17 MB, exact fit
    const size_t NEED = (size_t)((char*)(cb2 + CH) - ws);
    if (ws_size < NEED) return;

    bf16* lnX = (bf16*)d_out;  // d_out as bf16 scratch (dead before final writes)

    probe_k<<<1, 256, 0, stream>>>(x, flag);

    // 1. lnX = LN1(cpe0(x)) fused
    dwconv_ln<2, 0><<<dim3(Ww / 8, Hh, Bq), 384, 0, stream>>>(
        x, cpe0_w, cpe0_b, lnX, n1g, n1b, nullptr, nullptr, flag);

    // 2. lnS = LN1(cpe0(source)) fused -> MFMA gram partials -> reduce + hi/lo split
    dwconv_ln<2, 0><<<dim3(Ww / 8, Hh, Bq), 384, 0, stream>>>(
        srcp, cpe0_w, cpe0_b, lnS, n1g, n1b, nullptr, nullptr, flag);
    gram_mfma<<<dim3(9, NS, Bq), 256, 0, stream>>>((const u16t*)lnS, Gp);
    reduceG_k<<<(Bq * CcCc / 4) / 256, 256, 0, stream>>>(Gp, Gsplit);

    // 3. P_b = [Ghi|Glo] @ [Wv;Wv]  (split-precision MFMA, fp32 out; Wv = kv_w cols 384..767)
    transpose_k<<<dim3(6, 6), 256, 0, stream>>>(kv_w, WvT768, 768, 384, 768, 0, flag);
    transpose_k<<<dim3(6, 6), 256, 0, stream>>>(kv_w, WvT768, 768, 384, 768, 384, flag);
    gemm_mfma<2, false, 0, 0><<<dim3(3, 3, Bq), 256, 0, stream>>>(
        Gsplit, (size_t)Cc * 768, WvT768, 0, nullptr, nullptr, 0,
        nullptr, nullptr, nullptr, nullptr, P, CcCc, 0, 768, Cc, flag);

    // 4. attn: split-c partials (into dead s0) -> softmax -> fold into WeffT
    attn_part_k<<<dim3(NH, Bq, NSP), 256, 0, stream>>>(P, kv_w, Sp, flag);
    attn_soft_k<<<dim3(NH, Bq), 256, 0, stream>>>(Sp, attnB);
    wtilde_k<<<dim3(6, NH, Bq), 256, 0, stream>>>(q_w, attnB, Wt_, flag);
    transpose_k<<<dim3(6, 6), 256, 0, stream>>>(proj_w, projT, Cc, 0, Cc, 0, flag);
    gemm_mfma<1, false, 0, 0><<<dim3(3, 3, Bq), 256, 0, stream>>>(
        projT, 0, (const u16t*)Wt_, CcCc, nullptr, nullptr, 0,
        nullptr, nullptr, nullptr, nullptr, WeffT, CcCc, 0, Cc, Cc, flag);

    // MLP weight prep (P region free of Wt_ after Weff gemm; stream-ordered)
    transpose_scale_k<<<dim3(24, 6), 256, 0, stream>>>(fc1_w, n2g, fc1T, Cc, CH, flag);
    transpose_k<<<dim3(6, 24), 256, 0, stream>>>(fc2_w, fc2T, Cc, 0, CH, 0, flag);
    fc1fold_k<<<CH / 256, 256, 0, stream>>>(fc1_w, n2g, n2b, fc1_b, negc1, cb2, flag);

    // 5. x2 = lnX + lnX @ Weff_b + proj_b   (plain MFMA, RES=2 adds A element)
    gemm_mfma<1, false, 2, 0><<<dim3(32, 3, Bq), 256, 0, stream>>>(
        (const u16t*)lnX, NnCc, WeffT, CcCc, proj_b, nullptr, 0,
        nullptr, nullptr, nullptr, nullptr, x2, NnCc, 0, Cc, Cc, flag);

    // 6. x3 = cpe1(x2) raw + LN2 stats (fused)
    dwconv_ln<1, 1><<<dim3(Ww / 8, Hh, Bq), 384, 0, stream>>>(
        x2, cpe1_w, cpe1_b, x3, nullptr, nullptr, mu2, rs2, flag);

    // 7. MLP in 8192-row chunks: out = x3 + gelu(LN2(x3)@fc1+b1)@fc2+b2
    //    fc1 = plain GEMM on raw x3 with LN folded: gelu(rs*(x3@(g.fc1) + mu*negc1) + cb2)
    constexpr int CR = 8192;
    for (int ch = 0; ch < Mrows / CR; ch++) {
        size_t roff = (size_t)ch * CR;
        gemm_mfma<1, true, 0, 1><<<dim3(CR / 128, CH / 128, 1), 256, 0, stream>>>(
            (const u16t*)x3 + roff * Cc, 0, fc1T, 0, nullptr, nullptr, 0,
            mu2 + roff, rs2 + roff, negc1, cb2, h1c, 0, 0, Cc, CH, flag);
        gemm_mfma<0, false, 1, 0><<<dim3(CR / 128, Cc / 128, 1), 256, 0, stream>>>(
            h1c, 0, fc2T, 0, fc2_b, (const u16t*)x3 + roff * Cc, 0,
            nullptr, nullptr, nullptr, nullptr, d_out, 0, roff, CH, Cc, flag);
    }
}